// Round 1
// baseline (8625.381 us; speedup 1.0000x reference)
//
#include <hip/hip_runtime.h>
#include <math.h>

// Problem constants
constexpr int Tn = 43;      // sequence length
constexpr int Hd = 1024;    // hidden
constexpr int Dk = 512;     // head dim (DK == DV)
constexpr int Ff = 4096;    // FFN dim
constexpr int Nb = 512;     // batch

// ---------------------------------------------------------------------------
// embed: x[r,:] = emb[tok[r],:] + pos[t,:]
// ---------------------------------------------------------------------------
__global__ __launch_bounds__(256)
void embed_kernel(const int* __restrict__ toks, const float* __restrict__ emb,
                  const float* __restrict__ pos, float* __restrict__ X,
                  int n0, int Mc)
{
    int r = blockIdx.x;                 // chunk-local row
    int nl = r / Tn, t = r - nl * Tn;
    int tok = toks[(n0 + nl) * Tn + t];
    const float4* e = (const float4*)(emb + (long long)tok * Hd);
    const float4* p = (const float4*)(pos + (long long)t * Hd);
    float4* o = (float4*)(X + (long long)r * Hd);
    int i = threadIdx.x;                // 256 threads * float4 = 1024 floats
    float4 ev = e[i], pv = p[i];
    o[i] = make_float4(ev.x + pv.x, ev.y + pv.y, ev.z + pv.z, ev.w + pv.w);
}

// ---------------------------------------------------------------------------
// fp32 tiled GEMM: C[M,N] = A[M,K] @ B[K,N] + bias (+res) (ReLU optional)
// 64x64 tile, 256 threads, 4x4 microtile, BK=16.
// ---------------------------------------------------------------------------
template<bool RELU, bool HASRES>
__global__ __launch_bounds__(256)
void gemm64(const float* __restrict__ A, const float* __restrict__ B,
            const float* __restrict__ bias, const float* __restrict__ res,
            float* __restrict__ C, int M, int N, int K)
{
    __shared__ float As[16][68];   // [k][m], pad 68: stride 272B (16B-aligned, 2-way banks = free)
    __shared__ float Bs[16][68];   // [k][n]
    const int tid = threadIdx.x;
    const int tx = tid & 15, ty = tid >> 4;
    const int bm = blockIdx.x << 6, bn = blockIdx.y << 6;
    const int ar = tid >> 2, ak = (tid & 3) << 2;      // A: 64 rows x 16 k, float4/thread
    const int bk = tid >> 4, bc = (tid & 15) << 2;     // B: 16 k x 64 cols, float4/thread

    const int arow = bm + ar;
    const bool aval = arow < M;
    const float* Ap = A + (long long)arow * K + ak;
    const float* Bp = B + (long long)bk * N + bn + bc;

    float c[4][4] = {};

    for (int k0 = 0; k0 < K; k0 += 16) {
        float4 av = aval ? *(const float4*)Ap : make_float4(0.f, 0.f, 0.f, 0.f);
        float4 bv = *(const float4*)Bp;
        Ap += 16;
        Bp += (long long)N << 4;
        As[ak + 0][ar] = av.x;
        As[ak + 1][ar] = av.y;
        As[ak + 2][ar] = av.z;
        As[ak + 3][ar] = av.w;
        *(float4*)&Bs[bk][bc] = bv;
        __syncthreads();
        #pragma unroll
        for (int kk = 0; kk < 16; ++kk) {
            float4 a4 = *(const float4*)&As[kk][ty << 2];
            float4 b4 = *(const float4*)&Bs[kk][tx << 2];
            float aa[4] = {a4.x, a4.y, a4.z, a4.w};
            float bb[4] = {b4.x, b4.y, b4.z, b4.w};
            #pragma unroll
            for (int i = 0; i < 4; ++i)
                #pragma unroll
                for (int j = 0; j < 4; ++j)
                    c[i][j] = fmaf(aa[i], bb[j], c[i][j]);
        }
        __syncthreads();
    }

    const int col = bn + (tx << 2);
    float4 bia = *(const float4*)(bias + col);
    #pragma unroll
    for (int i = 0; i < 4; ++i) {
        int row = bm + (ty << 2) + i;
        if (row >= M) continue;
        float4 v = make_float4(c[i][0] + bia.x, c[i][1] + bia.y,
                               c[i][2] + bia.z, c[i][3] + bia.w);
        if (HASRES) {
            float4 r4 = *(const float4*)(res + (long long)row * N + col);
            v.x += r4.x; v.y += r4.y; v.z += r4.z; v.w += r4.w;
        }
        if (RELU) {
            v.x = fmaxf(v.x, 0.f); v.y = fmaxf(v.y, 0.f);
            v.z = fmaxf(v.z, 0.f); v.w = fmaxf(v.w, 0.f);
        }
        *(float4*)(C + (long long)row * N + col) = v;
    }
}

// ---------------------------------------------------------------------------
// attention: one block per (t, head, n). scores(43) -> softmax -> @V
// QKV layout: [Q1|K1|V1|Q2|K2|V2], each Mc x 512 row-major.
// Output written into concat buffer (Mc x 1024), head h -> cols [h*512, h*512+512)
// ---------------------------------------------------------------------------
__global__ __launch_bounds__(256)
void attn_kernel(const float* __restrict__ QKV, float* __restrict__ Cc, int Mc)
{
    const int t = blockIdx.x, h = blockIdx.y, nl = blockIdx.z;
    const long long hb = (long long)h * 3 * Mc * Dk;
    const float* Q = QKV + hb + (long long)(nl * Tn + t) * Dk;
    const float* K = QKV + hb + (long long)Mc * Dk + (long long)nl * Tn * Dk;
    const float* V = QKV + hb + 2LL * Mc * Dk + (long long)nl * Tn * Dk;

    __shared__ float qs[Dk];
    __shared__ float sc[48];

    const int tid = threadIdx.x;
    *(float2*)(qs + tid * 2) = *(const float2*)(Q + tid * 2);
    __syncthreads();

    const int wave = tid >> 6, lane = tid & 63;
    for (int s = wave; s < Tn; s += 4) {
        const float* Kr = K + (long long)s * Dk + lane * 8;
        float4 k0 = *(const float4*)Kr;
        float4 k1 = *(const float4*)(Kr + 4);
        const float* q = qs + lane * 8;
        float d = q[0]*k0.x + q[1]*k0.y + q[2]*k0.z + q[3]*k0.w
                + q[4]*k1.x + q[5]*k1.y + q[6]*k1.z + q[7]*k1.w;
        #pragma unroll
        for (int off = 32; off; off >>= 1) d += __shfl_xor(d, off);
        if (lane == 0) sc[s] = d * 0.044194173824159216f;  // 1/sqrt(512)
    }
    __syncthreads();
    if (tid < 64) {
        float v = (tid < Tn) ? sc[tid] : -INFINITY;
        float mx = v;
        #pragma unroll
        for (int off = 32; off; off >>= 1) mx = fmaxf(mx, __shfl_xor(mx, off));
        float e = (tid < Tn) ? expf(v - mx) : 0.f;
        float sum = e;
        #pragma unroll
        for (int off = 32; off; off >>= 1) sum += __shfl_xor(sum, off);
        if (tid < Tn) sc[tid] = e / sum;
    }
    __syncthreads();

    float2 acc = make_float2(0.f, 0.f);
    const int d0 = tid * 2;
    for (int s = 0; s < Tn; ++s) {
        float p = sc[s];
        float2 vv = *(const float2*)(V + (long long)s * Dk + d0);
        acc.x = fmaf(p, vv.x, acc.x);
        acc.y = fmaf(p, vv.y, acc.y);
    }
    *(float2*)(Cc + (long long)(nl * Tn + t) * (2 * Dk) + h * Dk + d0) = acc;
}

// ---------------------------------------------------------------------------
// LayerNorm (in place), one block per row of 1024
// ---------------------------------------------------------------------------
__global__ __launch_bounds__(256)
void ln_kernel(float* __restrict__ X, const float* __restrict__ g,
               const float* __restrict__ b)
{
    const int tid = threadIdx.x;
    float4* row = (float4*)(X + (long long)blockIdx.x * Hd);
    float4 v = row[tid];
    float s = v.x + v.y + v.z + v.w;
    float q = v.x*v.x + v.y*v.y + v.z*v.z + v.w*v.w;
    #pragma unroll
    for (int off = 32; off; off >>= 1) {
        s += __shfl_xor(s, off);
        q += __shfl_xor(q, off);
    }
    __shared__ float ss[4], sq[4];
    const int lane = tid & 63, w = tid >> 6;
    if (lane == 0) { ss[w] = s; sq[w] = q; }
    __syncthreads();
    s = ss[0] + ss[1] + ss[2] + ss[3];
    q = sq[0] + sq[1] + sq[2] + sq[3];
    const float mean = s * (1.f / Hd);
    const float var = q * (1.f / Hd) - mean * mean;
    const float rstd = rsqrtf(var + 1e-5f);
    float4 gv = ((const float4*)g)[tid];
    float4 bv = ((const float4*)b)[tid];
    v.x = (v.x - mean) * rstd * gv.x + bv.x;
    v.y = (v.y - mean) * rstd * gv.y + bv.y;
    v.z = (v.z - mean) * rstd * gv.z + bv.z;
    v.w = (v.w - mean) * rstd * gv.w + bv.w;
    row[tid] = v;
}

// ---------------------------------------------------------------------------
// final: out[n] = sigmoid(h2[n, t=0, :] . fl_w + fl_b)
// ---------------------------------------------------------------------------
__global__ __launch_bounds__(256)
void final_kernel(const float* __restrict__ H2, const float* __restrict__ w,
                  const float* __restrict__ fb, float* __restrict__ out, int n0)
{
    const int tid = threadIdx.x;
    const float4* row = (const float4*)(H2 + (long long)blockIdx.x * Tn * Hd);
    float4 v = row[tid];
    float4 wv = ((const float4*)w)[tid];
    float s = v.x*wv.x + v.y*wv.y + v.z*wv.z + v.w*wv.w;
    #pragma unroll
    for (int off = 32; off; off >>= 1) s += __shfl_xor(s, off);
    __shared__ float ss[4];
    const int lane = tid & 63, wv_ = tid >> 6;
    if (lane == 0) ss[wv_] = s;
    __syncthreads();
    if (tid == 0) {
        float z = ss[0] + ss[1] + ss[2] + ss[3] + fb[0];
        out[n0 + blockIdx.x] = 1.f / (1.f + expf(-z));
    }
}

// ---------------------------------------------------------------------------
// host
// ---------------------------------------------------------------------------
extern "C" void kernel_launch(void* const* d_in, const int* in_sizes, int n_in,
                              void* d_out, int out_size, void* d_ws, size_t ws_size,
                              hipStream_t stream)
{
    const int*   toks = (const int*)d_in[0];
    const float* emb  = (const float*)d_in[1];
    const float* pos  = (const float*)d_in[2];
    const float* q1w = (const float*)d_in[3];  const float* q1b = (const float*)d_in[4];
    const float* k1w = (const float*)d_in[5];  const float* k1b = (const float*)d_in[6];
    const float* v1w = (const float*)d_in[7];  const float* v1b = (const float*)d_in[8];
    const float* q2w = (const float*)d_in[9];  const float* q2b = (const float*)d_in[10];
    const float* k2w = (const float*)d_in[11]; const float* k2b = (const float*)d_in[12];
    const float* v2w = (const float*)d_in[13]; const float* v2b = (const float*)d_in[14];
    const float* pw  = (const float*)d_in[15]; const float* pb  = (const float*)d_in[16];
    const float* lg  = (const float*)d_in[17]; const float* lb  = (const float*)d_in[18];
    const float* w1w = (const float*)d_in[19]; const float* w1b = (const float*)d_in[20];
    const float* w2w = (const float*)d_in[21]; const float* w2b = (const float*)d_in[22];
    const float* flw = (const float*)d_in[23]; const float* flb = (const float*)d_in[24];
    float* out = (float*)d_out;
    float* ws  = (float*)d_ws;

    // per-sequence ws need: 43 rows * 6144 floats (x | qkv | attn-cat | h).
    // FFN intermediate (4096/row) exactly overlays qkv+attn-cat (3072+1024).
    const size_t bytes_per_seq = (size_t)Tn * 6144 * sizeof(float);
    int NC = (int)(ws_size / bytes_per_seq);
    if (NC > Nb) NC = Nb;
    if (NC < 1) NC = 1;

    for (int n0 = 0; n0 < Nb; n0 += NC) {
        const int nc = (Nb - n0 < NC) ? (Nb - n0) : NC;
        const int Mc = nc * Tn;
        float* X  = ws;                       // Mc*1024 : x, later h2
        float* Qk = X  + (size_t)Mc * Hd;     // Mc*3072 : Q1|K1|V1|Q2|K2|V2
        float* Cc = Qk + (size_t)Mc * 3072;   // Mc*1024 : attn concat
        float* Hb = Cc + (size_t)Mc * Hd;     // Mc*1024 : h
        float* E  = Qk;                       // Mc*4096 : FFN mid (overlays Qk+Cc)

        const int gm = (Mc + 63) >> 6;

        embed_kernel<<<Mc, 256, 0, stream>>>(toks, emb, pos, X, n0, Mc);

        const float* wq[6] = {q1w, k1w, v1w, q2w, k2w, v2w};
        const float* bq[6] = {q1b, k1b, v1b, q2b, k2b, v2b};
        for (int i = 0; i < 6; ++i)
            gemm64<false, false><<<dim3(gm, Dk / 64), 256, 0, stream>>>(
                X, wq[i], bq[i], nullptr, Qk + (size_t)i * Mc * Dk, Mc, Dk, Hd);

        attn_kernel<<<dim3(Tn, 2, nc), 256, 0, stream>>>(Qk, Cc, Mc);

        gemm64<false, true><<<dim3(gm, Hd / 64), 256, 0, stream>>>(
            Cc, pw, pb, X, Hb, Mc, Hd, Hd);
        ln_kernel<<<Mc, 256, 0, stream>>>(Hb, lg, lb);

        gemm64<true, false><<<dim3(gm, Ff / 64), 256, 0, stream>>>(
            Hb, w1w, w1b, nullptr, E, Mc, Ff, Hd);
        gemm64<false, true><<<dim3(gm, Hd / 64), 256, 0, stream>>>(
            E, w2w, w2b, Hb, X, Mc, Hd, Ff);
        ln_kernel<<<Mc, 256, 0, stream>>>(X, lg, lb);

        final_kernel<<<nc, 256, 0, stream>>>(X, flw, flb, out, n0);
    }
}

// Round 2
// 3163.821 us; speedup vs baseline: 2.7263x; 2.7263x over previous
//
#include <hip/hip_runtime.h>
#include <math.h>

typedef float  f32x4  __attribute__((ext_vector_type(4)));
typedef short  bf16x8 __attribute__((ext_vector_type(8)));
typedef unsigned short u16;
typedef unsigned int   u32;
typedef unsigned short u16x4 __attribute__((ext_vector_type(4)));
typedef unsigned short u16x8 __attribute__((ext_vector_type(8)));

constexpr int Tn = 43, Hd = 1024, Dk = 512, Ff = 4096, Nb = 512;

__device__ __forceinline__ u16 f2bf(float f) {
    u32 u = __float_as_uint(f);
    u32 r = u + 0x7FFFu + ((u >> 16) & 1u);
    return (u16)(r >> 16);
}
__device__ __forceinline__ float bf2f(u16 h) {
    return __uint_as_float(((u32)h) << 16);
}

// ---------------------------------------------------------------------------
// embed: x[r,:] = emb[tok[r],:] + pos[t,:]
// ---------------------------------------------------------------------------
__global__ __launch_bounds__(256)
void embed_kernel(const int* __restrict__ toks, const float* __restrict__ emb,
                  const float* __restrict__ pos, float* __restrict__ X,
                  int n0)
{
    int r = blockIdx.x;
    int nl = r / Tn, t = r - nl * Tn;
    int tok = toks[(n0 + nl) * Tn + t];
    const float4* e = (const float4*)(emb + (long long)tok * Hd);
    const float4* p = (const float4*)(pos + (long long)t * Hd);
    float4* o = (float4*)(X + (long long)r * Hd);
    int i = threadIdx.x;
    float4 ev = e[i], pv = p[i];
    o[i] = make_float4(ev.x + pv.x, ev.y + pv.y, ev.z + pv.z, ev.w + pv.w);
}

// ---------------------------------------------------------------------------
// activation fp32 -> bf16 hi/lo planes. Rows >= Mc (padding) -> zeros.
// Kc power of two, kshift = log2(Kc). total8 = Mp*Kc/8.
// ---------------------------------------------------------------------------
__global__ __launch_bounds__(256)
void conv_act(const float* __restrict__ X, u16* __restrict__ Hi,
              u16* __restrict__ Lo, int Mc, int kshift, int total8)
{
    int i = blockIdx.x * 256 + threadIdx.x;
    if (i >= total8) return;
    long long e = (long long)i * 8;
    int row = (int)(e >> kshift);
    u16x8 hv, lv;
    if (row < Mc) {
        const float4* p = (const float4*)(X + e);
        float4 v0 = p[0], v1 = p[1];
        float f[8] = {v0.x, v0.y, v0.z, v0.w, v1.x, v1.y, v1.z, v1.w};
        #pragma unroll
        for (int j = 0; j < 8; ++j) {
            u16 h = f2bf(f[j]);
            hv[j] = h;
            lv[j] = f2bf(f[j] - bf2f(h));
        }
    } else {
        #pragma unroll
        for (int j = 0; j < 8; ++j) { hv[j] = 0; lv[j] = 0; }
    }
    *(u16x8*)(Hi + e) = hv;
    *(u16x8*)(Lo + e) = lv;
}

// ---------------------------------------------------------------------------
// weight fp32 [K][N] -> transposed bf16 hi/lo planes [N][K]
// grid (K/32, N/32), 256 threads, LDS 32x32 tile transpose
// ---------------------------------------------------------------------------
__global__ __launch_bounds__(256)
void conv_w(const float* __restrict__ W, u16* __restrict__ THi,
            u16* __restrict__ TLo, int K, int N)
{
    __shared__ float tile[32][33];
    const int t = threadIdx.x;
    const int k0 = blockIdx.x * 32, n0 = blockIdx.y * 32;
    {
        int kk = t >> 3, nn = (t & 7) * 4;
        float4 v = *(const float4*)(W + (size_t)(k0 + kk) * N + n0 + nn);
        tile[kk][nn] = v.x; tile[kk][nn + 1] = v.y;
        tile[kk][nn + 2] = v.z; tile[kk][nn + 3] = v.w;
    }
    __syncthreads();
    {
        int nn = t >> 3, kk = (t & 7) * 4;
        u16x4 h, l;
        #pragma unroll
        for (int j = 0; j < 4; ++j) {
            float f = tile[kk + j][nn];
            u16 hh = f2bf(f);
            h[j] = hh;
            l[j] = f2bf(f - bf2f(hh));
        }
        size_t o = (size_t)(n0 + nn) * K + k0 + kk;
        *(u16x4*)(THi + o) = h;
        *(u16x4*)(TLo + o) = l;
    }
}

// ---------------------------------------------------------------------------
// MFMA GEMM: C[Mp][N] = (Ahi+Alo)[Mp][K] @ (Bhi+Blo)^T + bias (+res, relu)
// B planes stored transposed: [N][K]. 3-term split product.
// 128x128 tile, BK=32, 4 waves, 16x16x32 bf16 MFMA, XOR-swizzled LDS.
// ---------------------------------------------------------------------------
template<bool RELU, bool HASRES>
__global__ __launch_bounds__(256, 2)
void gemm_mfma(const u16* __restrict__ Ahi, const u16* __restrict__ Alo,
               const u16* __restrict__ Bhi, const u16* __restrict__ Blo,
               const float* __restrict__ bias, const float* __restrict__ res,
               float* __restrict__ C, int N, int K)
{
    __shared__ uint4 lds4[2048];          // 32 KB: Ahi|Alo|Bhi|Blo 8KB each
    char* lds = (char*)lds4;
    const int tid = threadIdx.x;
    const int bm = blockIdx.x << 7, bn = blockIdx.y << 7;
    const int r = tid >> 1, h = tid & 1;          // staging: row, k-half
    const int wv = tid >> 6, lane = tid & 63;
    const int wr = wv >> 1, wc = wv & 1;
    const int l15 = lane & 15, l4 = lane >> 4;

    const u16* pAh = Ahi + (size_t)(bm + r) * K + h * 16;
    const u16* pAl = Alo + (size_t)(bm + r) * K + h * 16;
    const u16* pBh = Bhi + (size_t)(bn + r) * K + h * 16;
    const u16* pBl = Blo + (size_t)(bn + r) * K + h * 16;

    const int swz = (r & 7) << 4;
    const int wb0 = (r * 64 + h * 32) ^ swz;
    const int wb1 = (r * 64 + h * 32 + 16) ^ swz;

    int fa[4], fb[4];
    #pragma unroll
    for (int m = 0; m < 4; ++m) {
        int rr = wr * 64 + m * 16 + l15;
        fa[m] = (rr * 64 + l4 * 16) ^ ((rr & 7) << 4);
    }
    #pragma unroll
    for (int n = 0; n < 4; ++n) {
        int rr = wc * 64 + n * 16 + l15;
        fb[n] = (rr * 64 + l4 * 16) ^ ((rr & 7) << 4);
    }

    f32x4 acc[4][4] = {};

    uint4 sA0 = *(const uint4*)(pAh), sA1 = *(const uint4*)(pAh + 8);
    uint4 sA2 = *(const uint4*)(pAl), sA3 = *(const uint4*)(pAl + 8);
    uint4 sB0 = *(const uint4*)(pBh), sB1 = *(const uint4*)(pBh + 8);
    uint4 sB2 = *(const uint4*)(pBl), sB3 = *(const uint4*)(pBl + 8);

    for (int k0 = 0; k0 < K; k0 += 32) {
        __syncthreads();
        *(uint4*)(lds + wb0)         = sA0; *(uint4*)(lds + wb1)         = sA1;
        *(uint4*)(lds + 8192 + wb0)  = sA2; *(uint4*)(lds + 8192 + wb1)  = sA3;
        *(uint4*)(lds + 16384 + wb0) = sB0; *(uint4*)(lds + 16384 + wb1) = sB1;
        *(uint4*)(lds + 24576 + wb0) = sB2; *(uint4*)(lds + 24576 + wb1) = sB3;
        __syncthreads();
        if (k0 + 32 < K) {
            pAh += 32; pAl += 32; pBh += 32; pBl += 32;
            sA0 = *(const uint4*)(pAh); sA1 = *(const uint4*)(pAh + 8);
            sA2 = *(const uint4*)(pAl); sA3 = *(const uint4*)(pAl + 8);
            sB0 = *(const uint4*)(pBh); sB1 = *(const uint4*)(pBh + 8);
            sB2 = *(const uint4*)(pBl); sB3 = *(const uint4*)(pBl + 8);
        }
        bf16x8 ah[4], al[4], bh[4], bl[4];
        #pragma unroll
        for (int m = 0; m < 4; ++m) {
            ah[m] = *(const bf16x8*)(lds + fa[m]);
            al[m] = *(const bf16x8*)(lds + 8192 + fa[m]);
        }
        #pragma unroll
        for (int n = 0; n < 4; ++n) {
            bh[n] = *(const bf16x8*)(lds + 16384 + fb[n]);
            bl[n] = *(const bf16x8*)(lds + 24576 + fb[n]);
        }
        #pragma unroll
        for (int m = 0; m < 4; ++m)
            #pragma unroll
            for (int n = 0; n < 4; ++n) {
                acc[m][n] = __builtin_amdgcn_mfma_f32_16x16x32_bf16(ah[m], bh[n], acc[m][n], 0, 0, 0);
                acc[m][n] = __builtin_amdgcn_mfma_f32_16x16x32_bf16(al[m], bh[n], acc[m][n], 0, 0, 0);
                acc[m][n] = __builtin_amdgcn_mfma_f32_16x16x32_bf16(ah[m], bl[n], acc[m][n], 0, 0, 0);
            }
    }

    #pragma unroll
    for (int n = 0; n < 4; ++n) {
        const int col = bn + wc * 64 + n * 16 + l15;
        const float bv = bias[col];
        #pragma unroll
        for (int m = 0; m < 4; ++m) {
            const int row0 = bm + wr * 64 + m * 16 + l4 * 4;
            #pragma unroll
            for (int rg = 0; rg < 4; ++rg) {
                const int row = row0 + rg;
                float v = acc[m][n][rg] + bv;
                if (HASRES) v += res[(size_t)row * N + col];
                if (RELU)   v = fmaxf(v, 0.f);
                C[(size_t)row * N + col] = v;
            }
        }
    }
}

// ---------------------------------------------------------------------------
// attention on fused QKV layout: Qk[row][3072], head h: Q@h*1536, K@+512, V@+1024
// one block per (t, head, n)
// ---------------------------------------------------------------------------
__global__ __launch_bounds__(256)
void attn_kernel(const float* __restrict__ Qk, float* __restrict__ Cc)
{
    const int t = blockIdx.x, h = blockIdx.y, nl = blockIdx.z;
    const float* Q  = Qk + (size_t)(nl * Tn + t) * 3072 + h * 1536;
    const float* Kb = Qk + (size_t)(nl * Tn) * 3072 + h * 1536 + 512;
    const float* Vb = Qk + (size_t)(nl * Tn) * 3072 + h * 1536 + 1024;

    __shared__ float qs[Dk];
    __shared__ float sc[48];

    const int tid = threadIdx.x;
    *(float2*)(qs + tid * 2) = *(const float2*)(Q + tid * 2);
    __syncthreads();

    const int wave = tid >> 6, lane = tid & 63;
    for (int s = wave; s < Tn; s += 4) {
        const float* Kr = Kb + (size_t)s * 3072 + lane * 8;
        float4 k0 = *(const float4*)Kr;
        float4 k1 = *(const float4*)(Kr + 4);
        const float* q = qs + lane * 8;
        float d = q[0]*k0.x + q[1]*k0.y + q[2]*k0.z + q[3]*k0.w
                + q[4]*k1.x + q[5]*k1.y + q[6]*k1.z + q[7]*k1.w;
        #pragma unroll
        for (int off = 32; off; off >>= 1) d += __shfl_xor(d, off);
        if (lane == 0) sc[s] = d * 0.044194173824159216f;
    }
    __syncthreads();
    if (tid < 64) {
        float v = (tid < Tn) ? sc[tid] : -INFINITY;
        float mx = v;
        #pragma unroll
        for (int off = 32; off; off >>= 1) mx = fmaxf(mx, __shfl_xor(mx, off));
        float e = (tid < Tn) ? expf(v - mx) : 0.f;
        float sum = e;
        #pragma unroll
        for (int off = 32; off; off >>= 1) sum += __shfl_xor(sum, off);
        if (tid < Tn) sc[tid] = e / sum;
    }
    __syncthreads();

    float2 acc = make_float2(0.f, 0.f);
    const int d0 = tid * 2;
    for (int s = 0; s < Tn; ++s) {
        float p = sc[s];
        float2 vv = *(const float2*)(Vb + (size_t)s * 3072 + d0);
        acc.x = fmaf(p, vv.x, acc.x);
        acc.y = fmaf(p, vv.y, acc.y);
    }
    *(float2*)(Cc + (size_t)(nl * Tn + t) * (2 * Dk) + h * Dk + d0) = acc;
}

// ---------------------------------------------------------------------------
// LayerNorm (in place), one block per row of 1024
// ---------------------------------------------------------------------------
__global__ __launch_bounds__(256)
void ln_kernel(float* __restrict__ X, const float* __restrict__ g,
               const float* __restrict__ b)
{
    const int tid = threadIdx.x;
    float4* row = (float4*)(X + (size_t)blockIdx.x * Hd);
    float4 v = row[tid];
    float s = v.x + v.y + v.z + v.w;
    float q = v.x*v.x + v.y*v.y + v.z*v.z + v.w*v.w;
    #pragma unroll
    for (int off = 32; off; off >>= 1) {
        s += __shfl_xor(s, off);
        q += __shfl_xor(q, off);
    }
    __shared__ float ss[4], sq[4];
    const int lane = tid & 63, w = tid >> 6;
    if (lane == 0) { ss[w] = s; sq[w] = q; }
    __syncthreads();
    s = ss[0] + ss[1] + ss[2] + ss[3];
    q = sq[0] + sq[1] + sq[2] + sq[3];
    const float mean = s * (1.f / Hd);
    const float var = q * (1.f / Hd) - mean * mean;
    const float rstd = rsqrtf(var + 1e-5f);
    float4 gv = ((const float4*)g)[tid];
    float4 bv = ((const float4*)b)[tid];
    v.x = (v.x - mean) * rstd * gv.x + bv.x;
    v.y = (v.y - mean) * rstd * gv.y + bv.y;
    v.z = (v.z - mean) * rstd * gv.z + bv.z;
    v.w = (v.w - mean) * rstd * gv.w + bv.w;
    row[tid] = v;
}

// ---------------------------------------------------------------------------
// final: out[n] = sigmoid(h2[n, t=0, :] . fl_w + fl_b)
// ---------------------------------------------------------------------------
__global__ __launch_bounds__(256)
void final_kernel(const float* __restrict__ H2, const float* __restrict__ w,
                  const float* __restrict__ fb, float* __restrict__ out, int n0)
{
    const int tid = threadIdx.x;
    const float4* row = (const float4*)(H2 + (size_t)blockIdx.x * Tn * Hd);
    float4 v = row[tid];
    float4 wv = ((const float4*)w)[tid];
    float s = v.x*wv.x + v.y*wv.y + v.z*wv.z + v.w*wv.w;
    #pragma unroll
    for (int off = 32; off; off >>= 1) s += __shfl_xor(s, off);
    __shared__ float ss[4];
    const int lane = tid & 63, wq = tid >> 6;
    if (lane == 0) ss[wq] = s;
    __syncthreads();
    if (tid == 0) {
        float z = ss[0] + ss[1] + ss[2] + ss[3] + fb[0];
        out[n0 + blockIdx.x] = 1.f / (1.f + expf(-z));
    }
}

// ---------------------------------------------------------------------------
// host
// ---------------------------------------------------------------------------
extern "C" void kernel_launch(void* const* d_in, const int* in_sizes, int n_in,
                              void* d_out, int out_size, void* d_ws, size_t ws_size,
                              hipStream_t stream)
{
    const int*   toks = (const int*)d_in[0];
    const float* emb  = (const float*)d_in[1];
    const float* pos  = (const float*)d_in[2];
    const float* q1w = (const float*)d_in[3];  const float* q1b = (const float*)d_in[4];
    const float* k1w = (const float*)d_in[5];  const float* k1b = (const float*)d_in[6];
    const float* v1w = (const float*)d_in[7];  const float* v1b = (const float*)d_in[8];
    const float* q2w = (const float*)d_in[9];  const float* q2b = (const float*)d_in[10];
    const float* k2w = (const float*)d_in[11]; const float* k2b = (const float*)d_in[12];
    const float* v2w = (const float*)d_in[13]; const float* v2b = (const float*)d_in[14];
    const float* pw  = (const float*)d_in[15]; const float* pb  = (const float*)d_in[16];
    const float* lg  = (const float*)d_in[17]; const float* lb  = (const float*)d_in[18];
    const float* w1w = (const float*)d_in[19]; const float* w1b = (const float*)d_in[20];
    const float* w2w = (const float*)d_in[21]; const float* w2b = (const float*)d_in[22];
    const float* flw = (const float*)d_in[23]; const float* flb = (const float*)d_in[24];
    float* out = (float*)d_out;
    char* wsb  = (char*)d_ws;

    // ---- fixed region: weight planes + concat bias ----
    size_t off = 0;
    auto alloc = [&](size_t bytes) { size_t o = off; off = (off + bytes + 255) & ~(size_t)255; return o; };
    u16* WqkvHi = (u16*)(wsb + alloc(3072 * 1024 * sizeof(u16)));
    u16* WqkvLo = (u16*)(wsb + alloc(3072 * 1024 * sizeof(u16)));
    u16* WpHi   = (u16*)(wsb + alloc(1024 * 1024 * sizeof(u16)));
    u16* WpLo   = (u16*)(wsb + alloc(1024 * 1024 * sizeof(u16)));
    u16* W1Hi   = (u16*)(wsb + alloc(4096 * 1024 * sizeof(u16)));
    u16* W1Lo   = (u16*)(wsb + alloc(4096 * 1024 * sizeof(u16)));
    u16* W2Hi   = (u16*)(wsb + alloc(1024 * 4096 * sizeof(u16)));
    u16* W2Lo   = (u16*)(wsb + alloc(1024 * 4096 * sizeof(u16)));
    float* bcat = (float*)(wsb + alloc(3072 * sizeof(float)));
    const size_t fixed_bytes = off;

    // per-row: X 4KB | QkCc/E 16KB | Hb 4KB | planes 16KB = 40KB
    const size_t row_bytes = 40960;
    int NC = (int)((ws_size > fixed_bytes ? ws_size - fixed_bytes : 0) / ((size_t)Tn * row_bytes + 128 * row_bytes / 43 + 1));
    // conservative: account padding by sizing with Mp_max below
    if (NC > Nb) NC = Nb;
    if (NC < 1) NC = 1;
    int Mp_max = ((NC * Tn + 127) / 128) * 128;
    while ((size_t)Mp_max * row_bytes + fixed_bytes > ws_size && NC > 1) {
        NC--; Mp_max = ((NC * Tn + 127) / 128) * 128;
    }

    float* X  = (float*)(wsb + alloc((size_t)Mp_max * 4096));
    float* Qk = (float*)(wsb + alloc((size_t)Mp_max * 16384));   // Qk (12KB) + Cc (4KB); later E (16KB)
    float* Hb = (float*)(wsb + alloc((size_t)Mp_max * 4096));
    u16*  Pb  = (u16*) (wsb + alloc((size_t)Mp_max * 16384));    // activation planes

    // ---- weight conversion (once per launch) ----
    const float* wq[6] = {q1w, k1w, v1w, q2w, k2w, v2w};
    for (int i = 0; i < 6; ++i)
        conv_w<<<dim3(1024 / 32, 512 / 32), 256, 0, stream>>>(
            wq[i], WqkvHi + (size_t)i * 512 * 1024, WqkvLo + (size_t)i * 512 * 1024, 1024, 512);
    conv_w<<<dim3(32, 32), 256, 0, stream>>>(pw, WpHi, WpLo, 1024, 1024);
    conv_w<<<dim3(32, 128), 256, 0, stream>>>(w1w, W1Hi, W1Lo, 1024, 4096);
    conv_w<<<dim3(128, 32), 256, 0, stream>>>(w2w, W2Hi, W2Lo, 4096, 1024);

    const float* bq[6] = {q1b, k1b, v1b, q2b, k2b, v2b};
    for (int i = 0; i < 6; ++i)
        hipMemcpyAsync(bcat + i * 512, bq[i], 512 * sizeof(float),
                       hipMemcpyDeviceToDevice, stream);

    for (int n0 = 0; n0 < Nb; n0 += NC) {
        const int nc = (Nb - n0 < NC) ? (Nb - n0) : NC;
        const int Mc = nc * Tn;
        const int Mp = ((Mc + 127) / 128) * 128;
        float* Cc = Qk + (size_t)Mp * 3072;       // after Qk within the 16KB region
        float* E  = Qk;                            // overlays Qk+Cc
        u16* XHi = Pb;                 u16* XLo = Pb + (size_t)Mp * 1024;   // reused for Cc, Hb planes
        u16* EHi = Pb;                 u16* ELo = Pb + (size_t)Mp * 4096;

        const int gm = Mp / 128;
        const int cgrid1k = Mp * 1024 / 2048;     // conv_act blocks for Kc=1024
        const int cgrid4k = Mp * 4096 / 2048;

        embed_kernel<<<Mc, 256, 0, stream>>>(toks, emb, pos, X, n0);

        conv_act<<<cgrid1k, 256, 0, stream>>>(X, XHi, XLo, Mc, 10, Mp * 1024 / 8);
        gemm_mfma<false, false><<<dim3(gm, 24), 256, 0, stream>>>(
            XHi, XLo, WqkvHi, WqkvLo, bcat, nullptr, Qk, 3072, 1024);

        attn_kernel<<<dim3(Tn, 2, nc), 256, 0, stream>>>(Qk, Cc);

        conv_act<<<cgrid1k, 256, 0, stream>>>(Cc, XHi, XLo, Mc, 10, Mp * 1024 / 8);
        gemm_mfma<false, true><<<dim3(gm, 8), 256, 0, stream>>>(
            XHi, XLo, WpHi, WpLo, pb, X, Hb, 1024, 1024);
        ln_kernel<<<Mc, 256, 0, stream>>>(Hb, lg, lb);

        conv_act<<<cgrid1k, 256, 0, stream>>>(Hb, XHi, XLo, Mc, 10, Mp * 1024 / 8);
        gemm_mfma<true, false><<<dim3(gm, 32), 256, 0, stream>>>(
            XHi, XLo, W1Hi, W1Lo, w1b, nullptr, E, 4096, 1024);

        conv_act<<<cgrid4k, 256, 0, stream>>>(E, EHi, ELo, Mc, 12, Mp * 4096 / 8);
        gemm_mfma<false, true><<<dim3(gm, 8), 256, 0, stream>>>(
            EHi, ELo, W2Hi, W2Lo, w2b, Hb, X, 1024, 4096);
        ln_kernel<<<Mc, 256, 0, stream>>>(X, lg, lb);

        final_kernel<<<nc, 256, 0, stream>>>(X, flw, flb, out, n0);
    }
}

// Round 3
// 659.540 us; speedup vs baseline: 13.0779x; 4.7970x over previous
//
#include <hip/hip_runtime.h>
#include <math.h>

typedef float  f32x4  __attribute__((ext_vector_type(4)));
typedef short  bf16x8 __attribute__((ext_vector_type(8)));
typedef unsigned short u16;
typedef unsigned int   u32;
typedef unsigned short u16x4 __attribute__((ext_vector_type(4)));

constexpr int Tn = 43, Hd = 1024, Nb = 512;

__device__ __forceinline__ u16 f2bf(float f) {
    u32 u = __float_as_uint(f);
    u32 r = u + 0x7FFFu + ((u >> 16) & 1u);
    return (u16)(r >> 16);
}
__device__ __forceinline__ float bf2f(u16 h) {
    return __uint_as_float(((u32)h) << 16);
}

// ---------------------------------------------------------------------------
// embed: x = emb[tok] + pos -> bf16 hi/lo planes; CLS rows also kept fp32.
// one block per row.
// ---------------------------------------------------------------------------
__global__ __launch_bounds__(256)
void embed_kernel(const int* __restrict__ toks, const float* __restrict__ emb,
                  const float* __restrict__ pos, u16* __restrict__ XHi,
                  u16* __restrict__ XLo, float* __restrict__ Xcls, int s0)
{
    const int r = blockIdx.x;
    const int nl = r / Tn, t = r - nl * Tn;
    const int tok = toks[(s0 + nl) * Tn + t];
    const float4* e = (const float4*)(emb + (size_t)tok * Hd);
    const float4* p = (const float4*)(pos + (size_t)t * Hd);
    const int i = threadIdx.x;
    float4 ev = e[i], pv = p[i];
    float f[4] = {ev.x + pv.x, ev.y + pv.y, ev.z + pv.z, ev.w + pv.w};
    u16x4 hv, lv;
    #pragma unroll
    for (int j = 0; j < 4; ++j) {
        u16 h = f2bf(f[j]);
        hv[j] = h;
        lv[j] = f2bf(f[j] - bf2f(h));
    }
    *(u16x4*)(XHi + (size_t)r * Hd + i * 4) = hv;
    *(u16x4*)(XLo + (size_t)r * Hd + i * 4) = lv;
    if (t == 0)
        *(float4*)(Xcls + (size_t)nl * Hd + i * 4) = make_float4(f[0], f[1], f[2], f[3]);
}

// ---------------------------------------------------------------------------
// weight fp32 [K][N] -> transposed bf16 hi/lo planes [N][K]
// ---------------------------------------------------------------------------
__global__ __launch_bounds__(256)
void conv_w(const float* __restrict__ W, u16* __restrict__ THi,
            u16* __restrict__ TLo, int K, int N)
{
    __shared__ float tile[32][33];
    const int t = threadIdx.x;
    const int k0 = blockIdx.x * 32, n0 = blockIdx.y * 32;
    {
        int kk = t >> 3, nn = (t & 7) * 4;
        float4 v = *(const float4*)(W + (size_t)(k0 + kk) * N + n0 + nn);
        tile[kk][nn] = v.x; tile[kk][nn + 1] = v.y;
        tile[kk][nn + 2] = v.z; tile[kk][nn + 3] = v.w;
    }
    __syncthreads();
    {
        int nn = t >> 3, kk = (t & 7) * 4;
        u16x4 h, l;
        #pragma unroll
        for (int j = 0; j < 4; ++j) {
            float f = tile[kk + j][nn];
            u16 hh = f2bf(f);
            h[j] = hh;
            l[j] = f2bf(f - bf2f(hh));
        }
        size_t o = (size_t)(n0 + nn) * K + k0 + kk;
        *(u16x4*)(THi + o) = h;
        *(u16x4*)(TLo + o) = l;
    }
}

// ---------------------------------------------------------------------------
// MFMA GEMM, 3-term split product, 128x128 tile, BK=32, 4 waves.
// A planes row stride = lda. B planes [N][K]. 1D grid, XCD chunk-swizzled
// (gridDim.x % 8 == 0 guaranteed by caller).
// Epilogue: +bias, optional +res, optional relu; write fp32 C or bf16 planes.
// ---------------------------------------------------------------------------
template<bool RELU, bool HASRES, bool PLANES>
__global__ __launch_bounds__(256, 2)
void gemm_mfma(const u16* __restrict__ Ahi, const u16* __restrict__ Alo,
               size_t lda,
               const u16* __restrict__ Bhi, const u16* __restrict__ Blo,
               const float* __restrict__ bias, const float* __restrict__ res,
               float* __restrict__ C, u16* __restrict__ CHi,
               u16* __restrict__ CLo, int N, int K)
{
    __shared__ uint4 lds4[2048];          // 32 KB: Ahi|Alo|Bhi|Blo 8KB each
    char* lds = (char*)lds4;
    const int tid = threadIdx.x;

    // bijective XCD chunk swizzle (nb % 8 == 0)
    const int nb = gridDim.x;
    const int q8 = nb >> 3;
    const int sw = (blockIdx.x & 7) * q8 + (blockIdx.x >> 3);
    const int ncol = N >> 7;
    const int bm = (sw / ncol) << 7, bn = (sw % ncol) << 7;

    const int r = tid >> 1, h = tid & 1;          // staging: row, k-half
    const int wv = tid >> 6, lane = tid & 63;
    const int wr = wv >> 1, wc = wv & 1;
    const int l15 = lane & 15, l4 = lane >> 4;

    const u16* pAh = Ahi + (size_t)(bm + r) * lda + h * 16;
    const u16* pAl = Alo + (size_t)(bm + r) * lda + h * 16;
    const u16* pBh = Bhi + (size_t)(bn + r) * K + h * 16;
    const u16* pBl = Blo + (size_t)(bn + r) * K + h * 16;

    const int swz = (r & 7) << 4;
    const int wb0 = (r * 64 + h * 32) ^ swz;
    const int wb1 = (r * 64 + h * 32 + 16) ^ swz;

    int fa[4], fb[4];
    #pragma unroll
    for (int m = 0; m < 4; ++m) {
        int rr = wr * 64 + m * 16 + l15;
        fa[m] = (rr * 64 + l4 * 16) ^ ((rr & 7) << 4);
    }
    #pragma unroll
    for (int n = 0; n < 4; ++n) {
        int rr = wc * 64 + n * 16 + l15;
        fb[n] = (rr * 64 + l4 * 16) ^ ((rr & 7) << 4);
    }

    f32x4 acc[4][4] = {};

    uint4 sA0 = *(const uint4*)(pAh), sA1 = *(const uint4*)(pAh + 8);
    uint4 sA2 = *(const uint4*)(pAl), sA3 = *(const uint4*)(pAl + 8);
    uint4 sB0 = *(const uint4*)(pBh), sB1 = *(const uint4*)(pBh + 8);
    uint4 sB2 = *(const uint4*)(pBl), sB3 = *(const uint4*)(pBl + 8);

    for (int k0 = 0; k0 < K; k0 += 32) {
        __syncthreads();
        *(uint4*)(lds + wb0)         = sA0; *(uint4*)(lds + wb1)         = sA1;
        *(uint4*)(lds + 8192 + wb0)  = sA2; *(uint4*)(lds + 8192 + wb1)  = sA3;
        *(uint4*)(lds + 16384 + wb0) = sB0; *(uint4*)(lds + 16384 + wb1) = sB1;
        *(uint4*)(lds + 24576 + wb0) = sB2; *(uint4*)(lds + 24576 + wb1) = sB3;
        __syncthreads();
        if (k0 + 32 < K) {
            pAh += 32; pAl += 32; pBh += 32; pBl += 32;
            sA0 = *(const uint4*)(pAh); sA1 = *(const uint4*)(pAh + 8);
            sA2 = *(const uint4*)(pAl); sA3 = *(const uint4*)(pAl + 8);
            sB0 = *(const uint4*)(pBh); sB1 = *(const uint4*)(pBh + 8);
            sB2 = *(const uint4*)(pBl); sB3 = *(const uint4*)(pBl + 8);
        }
        bf16x8 ah[4], al[4], bh[4], bl[4];
        #pragma unroll
        for (int m = 0; m < 4; ++m) {
            ah[m] = *(const bf16x8*)(lds + fa[m]);
            al[m] = *(const bf16x8*)(lds + 8192 + fa[m]);
        }
        #pragma unroll
        for (int n = 0; n < 4; ++n) {
            bh[n] = *(const bf16x8*)(lds + 16384 + fb[n]);
            bl[n] = *(const bf16x8*)(lds + 24576 + fb[n]);
        }
        #pragma unroll
        for (int m = 0; m < 4; ++m)
            #pragma unroll
            for (int n = 0; n < 4; ++n) {
                acc[m][n] = __builtin_amdgcn_mfma_f32_16x16x32_bf16(ah[m], bh[n], acc[m][n], 0, 0, 0);
                acc[m][n] = __builtin_amdgcn_mfma_f32_16x16x32_bf16(al[m], bh[n], acc[m][n], 0, 0, 0);
                acc[m][n] = __builtin_amdgcn_mfma_f32_16x16x32_bf16(ah[m], bl[n], acc[m][n], 0, 0, 0);
            }
    }

    #pragma unroll
    for (int n = 0; n < 4; ++n) {
        const int col = bn + wc * 64 + n * 16 + l15;
        const float bv = bias[col];
        #pragma unroll
        for (int m = 0; m < 4; ++m) {
            const int row0 = bm + wr * 64 + m * 16 + l4 * 4;
            #pragma unroll
            for (int rg = 0; rg < 4; ++rg) {
                const int row = row0 + rg;
                float v = acc[m][n][rg] + bv;
                if (HASRES) v += res[(size_t)row * N + col];
                if (RELU)   v = fmaxf(v, 0.f);
                if (PLANES) {
                    u16 hh = f2bf(v);
                    CHi[(size_t)row * N + col] = hh;
                    CLo[(size_t)row * N + col] = f2bf(v - bf2f(hh));
                } else {
                    C[(size_t)row * N + col] = v;
                }
            }
        }
    }
}

// ---------------------------------------------------------------------------
// attention for CLS token only: block per (n, head).
// KV layout: [Mc][2048], head h: K at col h*1024, V at h*1024+512.
// Output written directly as bf16 hi/lo planes of the concat buffer [nc][1024].
// ---------------------------------------------------------------------------
__global__ __launch_bounds__(256)
void attn_kernel(const float* __restrict__ Qf, const float* __restrict__ KV,
                 u16* __restrict__ CcHi, u16* __restrict__ CcLo)
{
    const int n = blockIdx.x, h = blockIdx.y;
    const float* Q  = Qf + (size_t)n * Hd + h * 512;
    const float* Kb = KV + (size_t)(n * Tn) * 2048 + h * 1024;
    const float* Vb = Kb + 512;

    __shared__ float qs[512];
    __shared__ float sc[48];

    const int tid = threadIdx.x;
    *(float2*)(qs + tid * 2) = *(const float2*)(Q + tid * 2);
    __syncthreads();

    const int wave = tid >> 6, lane = tid & 63;
    for (int s = wave; s < Tn; s += 4) {
        const float* Kr = Kb + (size_t)s * 2048 + lane * 8;
        float4 k0 = *(const float4*)Kr;
        float4 k1 = *(const float4*)(Kr + 4);
        const float* q = qs + lane * 8;
        float d = q[0]*k0.x + q[1]*k0.y + q[2]*k0.z + q[3]*k0.w
                + q[4]*k1.x + q[5]*k1.y + q[6]*k1.z + q[7]*k1.w;
        #pragma unroll
        for (int off = 32; off; off >>= 1) d += __shfl_xor(d, off);
        if (lane == 0) sc[s] = d * 0.044194173824159216f;   // 1/sqrt(512)
    }
    __syncthreads();
    if (tid < 64) {
        float v = (tid < Tn) ? sc[tid] : -INFINITY;
        float mx = v;
        #pragma unroll
        for (int off = 32; off; off >>= 1) mx = fmaxf(mx, __shfl_xor(mx, off));
        float e = (tid < Tn) ? expf(v - mx) : 0.f;
        float sum = e;
        #pragma unroll
        for (int off = 32; off; off >>= 1) sum += __shfl_xor(sum, off);
        if (tid < Tn) sc[tid] = e / sum;
    }
    __syncthreads();

    float2 acc = make_float2(0.f, 0.f);
    const int d0 = tid * 2;
    for (int s = 0; s < Tn; ++s) {
        float p = sc[s];
        float2 vv = *(const float2*)(Vb + (size_t)s * 2048 + d0);
        acc.x = fmaf(p, vv.x, acc.x);
        acc.y = fmaf(p, vv.y, acc.y);
    }
    const size_t o = (size_t)n * Hd + h * 512 + d0;
    u16 h0 = f2bf(acc.x), h1 = f2bf(acc.y);
    CcHi[o] = h0;     CcHi[o + 1] = h1;
    CcLo[o] = f2bf(acc.x - bf2f(h0));
    CcLo[o + 1] = f2bf(acc.y - bf2f(h1));
}

// ---------------------------------------------------------------------------
// LayerNorm: in-place fp32 + bf16 hi/lo planes out. one block per row.
// ---------------------------------------------------------------------------
__global__ __launch_bounds__(256)
void ln_kernel(float* __restrict__ X, const float* __restrict__ g,
               const float* __restrict__ b, u16* __restrict__ PHi,
               u16* __restrict__ PLo)
{
    const int tid = threadIdx.x;
    float4* row = (float4*)(X + (size_t)blockIdx.x * Hd);
    float4 v = row[tid];
    float s = v.x + v.y + v.z + v.w;
    float q = v.x*v.x + v.y*v.y + v.z*v.z + v.w*v.w;
    #pragma unroll
    for (int off = 32; off; off >>= 1) {
        s += __shfl_xor(s, off);
        q += __shfl_xor(q, off);
    }
    __shared__ float ss[4], sq[4];
    const int lane = tid & 63, w = tid >> 6;
    if (lane == 0) { ss[w] = s; sq[w] = q; }
    __syncthreads();
    s = ss[0] + ss[1] + ss[2] + ss[3];
    q = sq[0] + sq[1] + sq[2] + sq[3];
    const float mean = s * (1.f / Hd);
    const float var = q * (1.f / Hd) - mean * mean;
    const float rstd = rsqrtf(var + 1e-5f);
    float4 gv = ((const float4*)g)[tid];
    float4 bv = ((const float4*)b)[tid];
    float f[4];
    f[0] = (v.x - mean) * rstd * gv.x + bv.x;
    f[1] = (v.y - mean) * rstd * gv.y + bv.y;
    f[2] = (v.z - mean) * rstd * gv.z + bv.z;
    f[3] = (v.w - mean) * rstd * gv.w + bv.w;
    row[tid] = make_float4(f[0], f[1], f[2], f[3]);
    u16x4 hv, lv;
    #pragma unroll
    for (int j = 0; j < 4; ++j) {
        u16 hh = f2bf(f[j]);
        hv[j] = hh;
        lv[j] = f2bf(f[j] - bf2f(hh));
    }
    *(u16x4*)(PHi + (size_t)blockIdx.x * Hd + tid * 4) = hv;
    *(u16x4*)(PLo + (size_t)blockIdx.x * Hd + tid * 4) = lv;
}

// ---------------------------------------------------------------------------
// final: LN + sigmoid head fused. one block per sequence.
// ---------------------------------------------------------------------------
__global__ __launch_bounds__(256)
void ln_final(const float* __restrict__ H2, const float* __restrict__ g,
              const float* __restrict__ b, const float* __restrict__ fw,
              const float* __restrict__ fb, float* __restrict__ out, int s0)
{
    const int tid = threadIdx.x;
    const float4* row = (const float4*)(H2 + (size_t)blockIdx.x * Hd);
    float4 v = row[tid];
    float s = v.x + v.y + v.z + v.w;
    float q = v.x*v.x + v.y*v.y + v.z*v.z + v.w*v.w;
    #pragma unroll
    for (int off = 32; off; off >>= 1) {
        s += __shfl_xor(s, off);
        q += __shfl_xor(q, off);
    }
    __shared__ float ss[4], sq[4], sd[4];
    const int lane = tid & 63, w = tid >> 6;
    if (lane == 0) { ss[w] = s; sq[w] = q; }
    __syncthreads();
    s = ss[0] + ss[1] + ss[2] + ss[3];
    q = sq[0] + sq[1] + sq[2] + sq[3];
    const float mean = s * (1.f / Hd);
    const float var = q * (1.f / Hd) - mean * mean;
    const float rstd = rsqrtf(var + 1e-5f);
    float4 gv = ((const float4*)g)[tid];
    float4 bv = ((const float4*)b)[tid];
    float4 wv = ((const float4*)fw)[tid];
    float d = ((v.x - mean) * rstd * gv.x + bv.x) * wv.x
            + ((v.y - mean) * rstd * gv.y + bv.y) * wv.y
            + ((v.z - mean) * rstd * gv.z + bv.z) * wv.z
            + ((v.w - mean) * rstd * gv.w + bv.w) * wv.w;
    #pragma unroll
    for (int off = 32; off; off >>= 1) d += __shfl_xor(d, off);
    if (lane == 0) sd[w] = d;
    __syncthreads();
    if (tid == 0) {
        float z = sd[0] + sd[1] + sd[2] + sd[3] + fb[0];
        out[s0 + blockIdx.x] = 1.f / (1.f + expf(-z));
    }
}

// ---------------------------------------------------------------------------
// host
// ---------------------------------------------------------------------------
extern "C" void kernel_launch(void* const* d_in, const int* in_sizes, int n_in,
                              void* d_out, int out_size, void* d_ws, size_t ws_size,
                              hipStream_t stream)
{
    const int*   toks = (const int*)d_in[0];
    const float* emb  = (const float*)d_in[1];
    const float* pos  = (const float*)d_in[2];
    const float* q1w = (const float*)d_in[3];  const float* q1b = (const float*)d_in[4];
    const float* k1w = (const float*)d_in[5];  const float* k1b = (const float*)d_in[6];
    const float* v1w = (const float*)d_in[7];  const float* v1b = (const float*)d_in[8];
    const float* q2w = (const float*)d_in[9];  const float* q2b = (const float*)d_in[10];
    const float* k2w = (const float*)d_in[11]; const float* k2b = (const float*)d_in[12];
    const float* v2w = (const float*)d_in[13]; const float* v2b = (const float*)d_in[14];
    const float* pw  = (const float*)d_in[15]; const float* pb  = (const float*)d_in[16];
    const float* lg  = (const float*)d_in[17]; const float* lb  = (const float*)d_in[18];
    const float* w1w = (const float*)d_in[19]; const float* w1b = (const float*)d_in[20];
    const float* w2w = (const float*)d_in[21]; const float* w2b = (const float*)d_in[22];
    const float* flw = (const float*)d_in[23]; const float* flb = (const float*)d_in[24];
    float* out = (float*)d_out;
    char* wsb  = (char*)d_ws;

    size_t off = 0;
    auto alloc = [&](size_t bytes) { size_t o = off; off = (off + bytes + 255) & ~(size_t)255; return o; };

    // fixed: weight planes + biases
    u16* WkvHi = (u16*)(wsb + alloc(2048 * 1024 * sizeof(u16)));
    u16* WkvLo = (u16*)(wsb + alloc(2048 * 1024 * sizeof(u16)));
    u16* WqHi  = (u16*)(wsb + alloc(1024 * 1024 * sizeof(u16)));
    u16* WqLo  = (u16*)(wsb + alloc(1024 * 1024 * sizeof(u16)));
    u16* WpHi  = (u16*)(wsb + alloc(1024 * 1024 * sizeof(u16)));
    u16* WpLo  = (u16*)(wsb + alloc(1024 * 1024 * sizeof(u16)));
    u16* W1Hi  = (u16*)(wsb + alloc(4096 * 1024 * sizeof(u16)));
    u16* W1Lo  = (u16*)(wsb + alloc(4096 * 1024 * sizeof(u16)));
    u16* W2Hi  = (u16*)(wsb + alloc(1024 * 4096 * sizeof(u16)));
    u16* W2Lo  = (u16*)(wsb + alloc(1024 * 4096 * sizeof(u16)));
    float* bkv = (float*)(wsb + alloc(2048 * sizeof(float)));
    float* bq  = (float*)(wsb + alloc(1024 * sizeof(float)));
    const size_t fixed_bytes = off;

    // chunk size in sequences (keeps Mc % 128 == 0: 43*NC/128 integral)
    auto chunk_bytes = [&](int nc) -> size_t {
        size_t Mc = (size_t)nc * Tn;
        return Mc * 12288 + (size_t)nc * 40960 + 4096;
    };
    int NC = 512;
    while (NC > 128 && fixed_bytes + chunk_bytes(NC) > ws_size) NC >>= 1;

    const size_t McMax = (size_t)NC * Tn;
    u16* XHi   = (u16*)(wsb + alloc(McMax * Hd * sizeof(u16)));
    u16* XLo   = (u16*)(wsb + alloc(McMax * Hd * sizeof(u16)));
    float* KV  = (float*)(wsb + alloc(McMax * 2048 * sizeof(float)));
    float* Qf  = (float*)(wsb + alloc((size_t)NC * Hd * sizeof(float)));
    float* Xcls= (float*)(wsb + alloc((size_t)NC * Hd * sizeof(float)));
    u16* CcHi  = (u16*)(wsb + alloc((size_t)NC * Hd * sizeof(u16)));
    u16* CcLo  = (u16*)(wsb + alloc((size_t)NC * Hd * sizeof(u16)));
    float* Hb  = (float*)(wsb + alloc((size_t)NC * Hd * sizeof(float)));
    u16* HbHi  = (u16*)(wsb + alloc((size_t)NC * Hd * sizeof(u16)));
    u16* HbLo  = (u16*)(wsb + alloc((size_t)NC * Hd * sizeof(u16)));
    u16* EHi   = (u16*)(wsb + alloc((size_t)NC * 4096 * sizeof(u16)));
    u16* ELo   = (u16*)(wsb + alloc((size_t)NC * 4096 * sizeof(u16)));
    float* H2  = (float*)(wsb + alloc((size_t)NC * Hd * sizeof(float)));

    // weight conversion (deterministic, once per launch)
    conv_w<<<dim3(32, 16), 256, 0, stream>>>(k1w, WkvHi,                WkvLo,                1024, 512);
    conv_w<<<dim3(32, 16), 256, 0, stream>>>(v1w, WkvHi +  512 * 1024, WkvLo +  512 * 1024, 1024, 512);
    conv_w<<<dim3(32, 16), 256, 0, stream>>>(k2w, WkvHi + 1024 * 1024, WkvLo + 1024 * 1024, 1024, 512);
    conv_w<<<dim3(32, 16), 256, 0, stream>>>(v2w, WkvHi + 1536 * 1024, WkvLo + 1536 * 1024, 1024, 512);
    conv_w<<<dim3(32, 16), 256, 0, stream>>>(q1w, WqHi,              WqLo,              1024, 512);
    conv_w<<<dim3(32, 16), 256, 0, stream>>>(q2w, WqHi + 512 * 1024, WqLo + 512 * 1024, 1024, 512);
    conv_w<<<dim3(32, 32),  256, 0, stream>>>(pw,  WpHi, WpLo, 1024, 1024);
    conv_w<<<dim3(32, 128), 256, 0, stream>>>(w1w, W1Hi, W1Lo, 1024, 4096);
    conv_w<<<dim3(128, 32), 256, 0, stream>>>(w2w, W2Hi, W2Lo, 4096, 1024);

    hipMemcpyAsync(bkv,        k1b, 512 * sizeof(float), hipMemcpyDeviceToDevice, stream);
    hipMemcpyAsync(bkv +  512, v1b, 512 * sizeof(float), hipMemcpyDeviceToDevice, stream);
    hipMemcpyAsync(bkv + 1024, k2b, 512 * sizeof(float), hipMemcpyDeviceToDevice, stream);
    hipMemcpyAsync(bkv + 1536, v2b, 512 * sizeof(float), hipMemcpyDeviceToDevice, stream);
    hipMemcpyAsync(bq,        q1b, 512 * sizeof(float), hipMemcpyDeviceToDevice, stream);
    hipMemcpyAsync(bq +  512, q2b, 512 * sizeof(float), hipMemcpyDeviceToDevice, stream);

    for (int s0 = 0; s0 < Nb; s0 += NC) {
        const int nc = (Nb - s0 < NC) ? (Nb - s0) : NC;
        const int Mc = nc * Tn;               // multiple of 128 for nc in {512,256,128}
        const int gmKV = (Mc / 128) * (2048 / 128);
        const int gmQ  = (nc / 128) * (1024 / 128);
        const int gmP  = (nc / 128) * (1024 / 128);
        const int gmW1 = (nc / 128) * (4096 / 128);
        const int gmW2 = (nc / 128) * (1024 / 128);

        embed_kernel<<<Mc, 256, 0, stream>>>(toks, emb, pos, XHi, XLo, Xcls, s0);

        // K,V for all tokens
        gemm_mfma<false, false, false><<<gmKV, 256, 0, stream>>>(
            XHi, XLo, (size_t)Hd, WkvHi, WkvLo, bkv, nullptr,
            KV, nullptr, nullptr, 2048, 1024);
        // Q for CLS rows only (A row stride = Tn*Hd)
        gemm_mfma<false, false, false><<<gmQ, 256, 0, stream>>>(
            XHi, XLo, (size_t)Tn * Hd, WqHi, WqLo, bq, nullptr,
            Qf, nullptr, nullptr, 1024, 1024);

        attn_kernel<<<dim3(nc, 2), 256, 0, stream>>>(Qf, KV, CcHi, CcLo);

        gemm_mfma<false, true, false><<<gmP, 256, 0, stream>>>(
            CcHi, CcLo, (size_t)Hd, WpHi, WpLo, pb, Xcls,
            Hb, nullptr, nullptr, 1024, 1024);
        ln_kernel<<<nc, 256, 0, stream>>>(Hb, lg, lb, HbHi, HbLo);

        gemm_mfma<true, false, true><<<gmW1, 256, 0, stream>>>(
            HbHi, HbLo, (size_t)Hd, W1Hi, W1Lo, w1b, nullptr,
            nullptr, EHi, ELo, 4096, 1024);
        gemm_mfma<false, true, false><<<gmW2, 256, 0, stream>>>(
            EHi, ELo, (size_t)4096, W2Hi, W2Lo, w2b, Hb,
            H2, nullptr, nullptr, 1024, 4096);

        ln_final<<<nc, 256, 0, stream>>>(H2, lg, lb, flw, flb, out, s0);
    }
}

// Round 4
// 281.117 us; speedup vs baseline: 30.6825x; 2.3461x over previous
//
#include <hip/hip_runtime.h>
#include <math.h>

typedef float  f32x4  __attribute__((ext_vector_type(4)));
typedef short  bf16x8 __attribute__((ext_vector_type(8)));
typedef unsigned short u16;
typedef unsigned int   u32;
typedef unsigned short u16x4 __attribute__((ext_vector_type(4)));

constexpr int Tn = 43, Hd = 1024, Nb = 512;

__device__ __forceinline__ u16 f2bf(float f) {
    u32 u = __float_as_uint(f);
    u32 r = u + 0x7FFFu + ((u >> 16) & 1u);
    return (u16)(r >> 16);
}
__device__ __forceinline__ float bf2f(u16 h) {
    return __uint_as_float(((u32)h) << 16);
}

// ---------------------------------------------------------------------------
// weight fp32 [K][N] -> transposed bf16 hi/lo planes [N][K]
// ---------------------------------------------------------------------------
__global__ __launch_bounds__(256)
void conv_w(const float* __restrict__ W, u16* __restrict__ THi,
            u16* __restrict__ TLo, int K, int N)
{
    __shared__ float tile[32][33];
    const int t = threadIdx.x;
    const int k0 = blockIdx.x * 32, n0 = blockIdx.y * 32;
    {
        int kk = t >> 3, nn = (t & 7) * 4;
        float4 v = *(const float4*)(W + (size_t)(k0 + kk) * N + n0 + nn);
        tile[kk][nn] = v.x; tile[kk][nn + 1] = v.y;
        tile[kk][nn + 2] = v.z; tile[kk][nn + 3] = v.w;
    }
    __syncthreads();
    {
        int nn = t >> 3, kk = (t & 7) * 4;
        u16x4 h, l;
        #pragma unroll
        for (int j = 0; j < 4; ++j) {
            float f = tile[kk + j][nn];
            u16 hh = f2bf(f);
            h[j] = hh;
            l[j] = f2bf(f - bf2f(hh));
        }
        size_t o = (size_t)(n0 + nn) * K + k0 + kk;
        *(u16x4*)(THi + o) = h;
        *(u16x4*)(TLo + o) = l;
    }
}

// ---------------------------------------------------------------------------
// natural-layout plane split (no transpose): W fp32 [total] -> hi/lo planes
// ---------------------------------------------------------------------------
__global__ __launch_bounds__(256)
void conv_nat(const float* __restrict__ W, u16* __restrict__ Hi,
              u16* __restrict__ Lo)
{
    const size_t e = ((size_t)blockIdx.x * 256 + threadIdx.x) * 8;
    const float4* p = (const float4*)(W + e);
    float4 v0 = p[0], v1 = p[1];
    float f[8] = {v0.x, v0.y, v0.z, v0.w, v1.x, v1.y, v1.z, v1.w};
    u16 hv[8], lv[8];
    #pragma unroll
    for (int j = 0; j < 8; ++j) {
        u16 h = f2bf(f[j]);
        hv[j] = h;
        lv[j] = f2bf(f[j] - bf2f(h));
    }
    *(u16x4*)(Hi + e)     = *(u16x4*)&hv[0];
    *(u16x4*)(Hi + e + 4) = *(u16x4*)&hv[4];
    *(u16x4*)(Lo + e)     = *(u16x4*)&lv[0];
    *(u16x4*)(Lo + e + 4) = *(u16x4*)&lv[4];
}

// ---------------------------------------------------------------------------
// CLS embed: x = emb[tok[n,0]] + pos[0] -> fp32 + bf16 hi/lo planes
// ---------------------------------------------------------------------------
__global__ __launch_bounds__(256)
void cls_embed(const int* __restrict__ toks, const float* __restrict__ emb,
               const float* __restrict__ pos, float* __restrict__ Xf,
               u16* __restrict__ XHi, u16* __restrict__ XLo)
{
    const int n = blockIdx.x, i = threadIdx.x;
    const int tok = toks[n * Tn];
    float4 e = ((const float4*)(emb + (size_t)tok * Hd))[i];
    float4 p = ((const float4*)pos)[i];
    float f[4] = {e.x + p.x, e.y + p.y, e.z + p.z, e.w + p.w};
    ((float4*)(Xf + (size_t)n * Hd))[i] = make_float4(f[0], f[1], f[2], f[3]);
    u16x4 hv, lv;
    #pragma unroll
    for (int j = 0; j < 4; ++j) {
        u16 h = f2bf(f[j]);
        hv[j] = h;
        lv[j] = f2bf(f[j] - bf2f(h));
    }
    *(u16x4*)(XHi + (size_t)n * Hd + i * 4) = hv;
    *(u16x4*)(XLo + (size_t)n * Hd + i * 4) = lv;
}

// ---------------------------------------------------------------------------
// MFMA GEMM, 3-term split, 64x128 tile, BK=32, 4 waves.
// Fragment-major LDS (conflict-free): chunk (rowgrp, kgrp, row16) of 16B.
// A [M][lda] planes, B [N][ldb] planes (transposed weights).
// SPLIT: gridDim.z K-chunks -> fp32 partials in Cp (no epilogue).
// ---------------------------------------------------------------------------
template<bool RELU, bool HASRES, bool PLANES, bool SPLIT>
__global__ __launch_bounds__(256, 2)
void gemm64(const u16* __restrict__ Ahi, const u16* __restrict__ Alo, int lda,
            const u16* __restrict__ Bhi, const u16* __restrict__ Blo, int ldb,
            const float* __restrict__ bias, const float* __restrict__ res,
            int ldres, float* __restrict__ C, u16* __restrict__ CHi,
            u16* __restrict__ CLo, int ldc, int N, int K,
            float* __restrict__ Cp, size_t pstride)
{
    __shared__ uint4 lds4[1536];          // 24 KB: Ahi 4K | Alo 4K | Bhi 8K | Blo 8K
    char* lds = (char*)lds4;
    const int tid = threadIdx.x;

    const int nbx = gridDim.x;
    const int q8 = nbx >> 3;
    const int sw = (blockIdx.x & 7) * q8 + (blockIdx.x >> 3);
    const int ncol = N >> 7;
    const int bm = (sw / ncol) << 6, bn = (sw % ncol) << 7;

    int kc = K, kb = 0;
    if (SPLIT) { kc = K / gridDim.z; kb = blockIdx.z * kc; }

    // staging: A: thread -> (row ra, 16B chunk ga). B: (row rb, chunks gb2,gb2+1)
    const int ra = tid >> 2, ga = tid & 3;
    const int rb = tid >> 1, gb2 = (tid & 1) << 1;
    const u16* pAh = Ahi + (size_t)(bm + ra) * lda + kb + ga * 8;
    const u16* pAl = Alo + (size_t)(bm + ra) * lda + kb + ga * 8;
    const u16* pBh = Bhi + (size_t)(bn + rb) * ldb + kb + gb2 * 8;
    const u16* pBl = Blo + (size_t)(bn + rb) * ldb + kb + gb2 * 8;

    const int wA = ((ra >> 4) << 10) + (ga << 8) + ((ra & 15) << 4);
    const int wB = ((rb >> 4) << 10) + (gb2 << 8) + ((rb & 15) << 4);

    const int wv = tid >> 6, lane = tid & 63;
    const int wr = wv >> 1, wc = wv & 1;
    const int l15 = lane & 15, l4 = lane >> 4;

    int fA[2], fB[4];
    #pragma unroll
    for (int m = 0; m < 2; ++m)
        fA[m] = (((wr << 1) + m) << 10) + (l4 << 8) + (l15 << 4);
    #pragma unroll
    for (int n = 0; n < 4; ++n)
        fB[n] = (((wc << 2) + n) << 10) + (l4 << 8) + (l15 << 4);

    f32x4 acc[2][4] = {};

    uint4 sAh = *(const uint4*)pAh;
    uint4 sAl = *(const uint4*)pAl;
    uint4 sBh0 = *(const uint4*)pBh, sBh1 = *(const uint4*)(pBh + 8);
    uint4 sBl0 = *(const uint4*)pBl, sBl1 = *(const uint4*)(pBl + 8);

    for (int k0 = 0; k0 < kc; k0 += 32) {
        __syncthreads();
        *(uint4*)(lds + wA)               = sAh;
        *(uint4*)(lds + 4096 + wA)        = sAl;
        *(uint4*)(lds + 8192 + wB)        = sBh0;
        *(uint4*)(lds + 8192 + wB + 256)  = sBh1;
        *(uint4*)(lds + 16384 + wB)       = sBl0;
        *(uint4*)(lds + 16384 + wB + 256) = sBl1;
        __syncthreads();
        if (k0 + 32 < kc) {
            pAh += 32; pAl += 32; pBh += 32; pBl += 32;
            sAh = *(const uint4*)pAh;
            sAl = *(const uint4*)pAl;
            sBh0 = *(const uint4*)pBh; sBh1 = *(const uint4*)(pBh + 8);
            sBl0 = *(const uint4*)pBl; sBl1 = *(const uint4*)(pBl + 8);
        }
        bf16x8 ah[2], al[2], bh[4], bl[4];
        #pragma unroll
        for (int m = 0; m < 2; ++m) {
            ah[m] = *(const bf16x8*)(lds + fA[m]);
            al[m] = *(const bf16x8*)(lds + 4096 + fA[m]);
        }
        #pragma unroll
        for (int n = 0; n < 4; ++n) {
            bh[n] = *(const bf16x8*)(lds + 8192 + fB[n]);
            bl[n] = *(const bf16x8*)(lds + 16384 + fB[n]);
        }
        #pragma unroll
        for (int m = 0; m < 2; ++m)
            #pragma unroll
            for (int n = 0; n < 4; ++n) {
                acc[m][n] = __builtin_amdgcn_mfma_f32_16x16x32_bf16(ah[m], bh[n], acc[m][n], 0, 0, 0);
                acc[m][n] = __builtin_amdgcn_mfma_f32_16x16x32_bf16(al[m], bh[n], acc[m][n], 0, 0, 0);
                acc[m][n] = __builtin_amdgcn_mfma_f32_16x16x32_bf16(ah[m], bl[n], acc[m][n], 0, 0, 0);
            }
    }

    #pragma unroll
    for (int n = 0; n < 4; ++n) {
        const int col = bn + (wc << 6) + n * 16 + l15;
        const float bv = SPLIT ? 0.f : bias[col];
        #pragma unroll
        for (int m = 0; m < 2; ++m) {
            const int row0 = bm + (wr << 5) + m * 16 + l4 * 4;
            #pragma unroll
            for (int rg = 0; rg < 4; ++rg) {
                const int row = row0 + rg;
                float v = acc[m][n][rg];
                if (SPLIT) {
                    Cp[blockIdx.z * pstride + (size_t)row * N + col] = v;
                } else {
                    v += bv;
                    if (HASRES) v += res[(size_t)row * ldres + col];
                    if (RELU)   v = fmaxf(v, 0.f);
                    if (PLANES) {
                        u16 hh = f2bf(v);
                        CHi[(size_t)row * ldc + col] = hh;
                        CLo[(size_t)row * ldc + col] = f2bf(v - bf2f(hh));
                    } else {
                        C[(size_t)row * ldc + col] = v;
                    }
                }
            }
        }
    }
}

// ---------------------------------------------------------------------------
// fused attention (CLS row only), direct from embedding gather.
// scores_s = (x_s . u_head) / sqrt(512)  (Q.bk shift cancels in softmax)
// y_head   = sum_s p_s x_s  -> bf16 planes [n][2048]
// one block per sequence.
// ---------------------------------------------------------------------------
__global__ __launch_bounds__(256)
void attn_direct(const int* __restrict__ toks, const float* __restrict__ emb,
                 const float* __restrict__ pos, const float* __restrict__ U,
                 u16* __restrict__ YHi, u16* __restrict__ YLo)
{
    const int n = blockIdx.x, tid = threadIdx.x;
    __shared__ float us[2048];
    __shared__ float ps[2][64];
    {
        const float4* up = (const float4*)(U + (size_t)n * 2048);
        ((float4*)us)[tid] = up[tid];
        ((float4*)us)[tid + 256] = up[tid + 256];
    }
    __syncthreads();

    const int wave = tid >> 6, lane = tid & 63;
    const int* tk = toks + n * Tn;
    for (int s = wave; s < Tn; s += 4) {
        const int tok = tk[s];
        const float4* er = (const float4*)(emb + (size_t)tok * Hd);
        const float4* pr = (const float4*)(pos + (size_t)s * Hd);
        float d1 = 0.f, d2 = 0.f;
        #pragma unroll
        for (int i = 0; i < 4; ++i) {
            const int c = lane * 4 + i;
            float4 e = er[c], p = pr[c];
            float x0 = e.x + p.x, x1 = e.y + p.y, x2 = e.z + p.z, x3 = e.w + p.w;
            const float* u1 = us + c * 4;
            const float* u2 = us + 1024 + c * 4;
            d1 += x0 * u1[0] + x1 * u1[1] + x2 * u1[2] + x3 * u1[3];
            d2 += x0 * u2[0] + x1 * u2[1] + x2 * u2[2] + x3 * u2[3];
        }
        #pragma unroll
        for (int off = 32; off; off >>= 1) {
            d1 += __shfl_xor(d1, off);
            d2 += __shfl_xor(d2, off);
        }
        if (lane == 0) {
            ps[0][s] = d1 * 0.044194173824159216f;
            ps[1][s] = d2 * 0.044194173824159216f;
        }
    }
    __syncthreads();
    if (wave < 2) {
        float v = (lane < Tn) ? ps[wave][lane] : -INFINITY;
        float mx = v;
        #pragma unroll
        for (int off = 32; off; off >>= 1) mx = fmaxf(mx, __shfl_xor(mx, off));
        float e = (lane < Tn) ? __expf(v - mx) : 0.f;
        float sum = e;
        #pragma unroll
        for (int off = 32; off; off >>= 1) sum += __shfl_xor(sum, off);
        if (lane < Tn) ps[wave][lane] = e / sum;
    }
    __syncthreads();

    float4 a1 = make_float4(0.f, 0.f, 0.f, 0.f);
    float4 a2 = make_float4(0.f, 0.f, 0.f, 0.f);
    for (int s = 0; s < Tn; ++s) {
        const int tok = tk[s];
        const float p1 = ps[0][s], p2 = ps[1][s];
        float4 e = ((const float4*)(emb + (size_t)tok * Hd))[tid];
        float4 p = ((const float4*)(pos + (size_t)s * Hd))[tid];
        float x0 = e.x + p.x, x1 = e.y + p.y, x2 = e.z + p.z, x3 = e.w + p.w;
        a1.x += p1 * x0; a1.y += p1 * x1; a1.z += p1 * x2; a1.w += p1 * x3;
        a2.x += p2 * x0; a2.y += p2 * x1; a2.z += p2 * x2; a2.w += p2 * x3;
    }
    float f1[4] = {a1.x, a1.y, a1.z, a1.w};
    float f2[4] = {a2.x, a2.y, a2.z, a2.w};
    u16x4 h1, l1, h2, l2;
    #pragma unroll
    for (int j = 0; j < 4; ++j) {
        u16 h = f2bf(f1[j]); h1[j] = h; l1[j] = f2bf(f1[j] - bf2f(h));
        h = f2bf(f2[j]);     h2[j] = h; l2[j] = f2bf(f2[j] - bf2f(h));
    }
    const size_t o = (size_t)n * 2048 + tid * 4;
    *(u16x4*)(YHi + o) = h1;          *(u16x4*)(YLo + o) = l1;
    *(u16x4*)(YHi + o + 1024) = h2;   *(u16x4*)(YLo + o + 1024) = l2;
}

// ---------------------------------------------------------------------------
// LayerNorm: in-place fp32 + bf16 hi/lo planes out. one block per row.
// ---------------------------------------------------------------------------
__global__ __launch_bounds__(256)
void ln_kernel(float* __restrict__ X, const float* __restrict__ g,
               const float* __restrict__ b, u16* __restrict__ PHi,
               u16* __restrict__ PLo)
{
    const int tid = threadIdx.x;
    float4* row = (float4*)(X + (size_t)blockIdx.x * Hd);
    float4 v = row[tid];
    float s = v.x + v.y + v.z + v.w;
    float q = v.x*v.x + v.y*v.y + v.z*v.z + v.w*v.w;
    #pragma unroll
    for (int off = 32; off; off >>= 1) {
        s += __shfl_xor(s, off);
        q += __shfl_xor(q, off);
    }
    __shared__ float ss[4], sq[4];
    const int lane = tid & 63, w = tid >> 6;
    if (lane == 0) { ss[w] = s; sq[w] = q; }
    __syncthreads();
    s = ss[0] + ss[1] + ss[2] + ss[3];
    q = sq[0] + sq[1] + sq[2] + sq[3];
    const float mean = s * (1.f / Hd);
    const float var = q * (1.f / Hd) - mean * mean;
    const float rstd = rsqrtf(var + 1e-5f);
    float4 gv = ((const float4*)g)[tid];
    float4 bv = ((const float4*)b)[tid];
    float f[4];
    f[0] = (v.x - mean) * rstd * gv.x + bv.x;
    f[1] = (v.y - mean) * rstd * gv.y + bv.y;
    f[2] = (v.z - mean) * rstd * gv.z + bv.z;
    f[3] = (v.w - mean) * rstd * gv.w + bv.w;
    row[tid] = make_float4(f[0], f[1], f[2], f[3]);
    u16x4 hv, lv;
    #pragma unroll
    for (int j = 0; j < 4; ++j) {
        u16 hh = f2bf(f[j]);
        hv[j] = hh;
        lv[j] = f2bf(f[j] - bf2f(hh));
    }
    *(u16x4*)(PHi + (size_t)blockIdx.x * Hd + tid * 4) = hv;
    *(u16x4*)(PLo + (size_t)blockIdx.x * Hd + tid * 4) = lv;
}

// ---------------------------------------------------------------------------
// w2 split-K reduce: H2 = sum_z Cp[z] + w2b + Hb
// ---------------------------------------------------------------------------
__global__ __launch_bounds__(256)
void w2_reduce(const float* __restrict__ Cp, const float* __restrict__ bias,
               const float* __restrict__ Hb, float* __restrict__ H2)
{
    const int idx = blockIdx.x * 256 + threadIdx.x;   // float4 index
    const size_t P = (size_t)Nb * Hd / 4;
    const float4* cp = (const float4*)Cp;
    float4 v0 = cp[idx], v1 = cp[idx + P], v2 = cp[idx + 2*P], v3 = cp[idx + 3*P];
    const int col4 = idx & 255;
    float4 b = ((const float4*)bias)[col4];
    float4 h = ((const float4*)Hb)[idx];
    float4 r;
    r.x = v0.x + v1.x + v2.x + v3.x + b.x + h.x;
    r.y = v0.y + v1.y + v2.y + v3.y + b.y + h.y;
    r.z = v0.z + v1.z + v2.z + v3.z + b.z + h.z;
    r.w = v0.w + v1.w + v2.w + v3.w + b.w + h.w;
    ((float4*)H2)[idx] = r;
}

// ---------------------------------------------------------------------------
// final: LN + sigmoid head fused. one block per sequence.
// ---------------------------------------------------------------------------
__global__ __launch_bounds__(256)
void ln_final(const float* __restrict__ H2, const float* __restrict__ g,
              const float* __restrict__ b, const float* __restrict__ fw,
              const float* __restrict__ fb, float* __restrict__ out)
{
    const int tid = threadIdx.x;
    const float4* row = (const float4*)(H2 + (size_t)blockIdx.x * Hd);
    float4 v = row[tid];
    float s = v.x + v.y + v.z + v.w;
    float q = v.x*v.x + v.y*v.y + v.z*v.z + v.w*v.w;
    #pragma unroll
    for (int off = 32; off; off >>= 1) {
        s += __shfl_xor(s, off);
        q += __shfl_xor(q, off);
    }
    __shared__ float ss[4], sq[4], sd[4];
    const int lane = tid & 63, w = tid >> 6;
    if (lane == 0) { ss[w] = s; sq[w] = q; }
    __syncthreads();
    s = ss[0] + ss[1] + ss[2] + ss[3];
    q = sq[0] + sq[1] + sq[2] + sq[3];
    const float mean = s * (1.f / Hd);
    const float var = q * (1.f / Hd) - mean * mean;
    const float rstd = rsqrtf(var + 1e-5f);
    float4 gv = ((const float4*)g)[tid];
    float4 bv = ((const float4*)b)[tid];
    float4 wv = ((const float4*)fw)[tid];
    float d = ((v.x - mean) * rstd * gv.x + bv.x) * wv.x
            + ((v.y - mean) * rstd * gv.y + bv.y) * wv.y
            + ((v.z - mean) * rstd * gv.z + bv.z) * wv.z
            + ((v.w - mean) * rstd * gv.w + bv.w) * wv.w;
    #pragma unroll
    for (int off = 32; off; off >>= 1) d += __shfl_xor(d, off);
    if (lane == 0) sd[w] = d;
    __syncthreads();
    if (tid == 0) {
        float z = sd[0] + sd[1] + sd[2] + sd[3] + fb[0];
        out[blockIdx.x] = 1.f / (1.f + expf(-z));
    }
}

// ---------------------------------------------------------------------------
// host
// ---------------------------------------------------------------------------
extern "C" void kernel_launch(void* const* d_in, const int* in_sizes, int n_in,
                              void* d_out, int out_size, void* d_ws, size_t ws_size,
                              hipStream_t stream)
{
    const int*   toks = (const int*)d_in[0];
    const float* emb  = (const float*)d_in[1];
    const float* pos  = (const float*)d_in[2];
    const float* q1w = (const float*)d_in[3];
    const float* k1w = (const float*)d_in[5];
    const float* v1w = (const float*)d_in[7];  const float* v1b = (const float*)d_in[8];
    const float* q2w = (const float*)d_in[9];
    const float* k2w = (const float*)d_in[11];
    const float* v2w = (const float*)d_in[13]; const float* v2b = (const float*)d_in[14];
    const float* pw  = (const float*)d_in[15]; const float* pb  = (const float*)d_in[16];
    const float* lg  = (const float*)d_in[17]; const float* lb  = (const float*)d_in[18];
    const float* w1w = (const float*)d_in[19]; const float* w1b = (const float*)d_in[20];
    const float* w2w = (const float*)d_in[21]; const float* w2b = (const float*)d_in[22];
    const float* flw = (const float*)d_in[23]; const float* flb = (const float*)d_in[24];
    float* out = (float*)d_out;
    char* wsb  = (char*)d_ws;

    size_t off = 0;
    auto alloc = [&](size_t bytes) { size_t o = off; off = (off + bytes + 255) & ~(size_t)255; return o; };

    // weight planes
    u16* WvTHi = (u16*)(wsb + alloc(2 * 512 * 1024 * sizeof(u16)));
    u16* WvTLo = (u16*)(wsb + alloc(2 * 512 * 1024 * sizeof(u16)));
    u16* WpTHi = (u16*)(wsb + alloc(1024 * 1024 * sizeof(u16)));
    u16* WpTLo = (u16*)(wsb + alloc(1024 * 1024 * sizeof(u16)));
    u16* W1THi = (u16*)(wsb + alloc(4096 * 1024 * sizeof(u16)));
    u16* W1TLo = (u16*)(wsb + alloc(4096 * 1024 * sizeof(u16)));
    u16* W2THi = (u16*)(wsb + alloc(1024 * 4096 * sizeof(u16)));
    u16* W2TLo = (u16*)(wsb + alloc(1024 * 4096 * sizeof(u16)));
    u16* WkNHi = (u16*)(wsb + alloc(2 * 1024 * 512 * sizeof(u16)));
    u16* WkNLo = (u16*)(wsb + alloc(2 * 1024 * 512 * sizeof(u16)));
    u16* WqNHi = (u16*)(wsb + alloc(2 * 1024 * 512 * sizeof(u16)));
    u16* WqNLo = (u16*)(wsb + alloc(2 * 1024 * 512 * sizeof(u16)));
    u16* GHi   = (u16*)(wsb + alloc(2048 * 1024 * sizeof(u16)));
    u16* GLo   = (u16*)(wsb + alloc(2048 * 1024 * sizeof(u16)));
    float* zeros = (float*)(wsb + alloc(2048 * sizeof(float)));

    // activations (M = 512 everywhere)
    float* XclsF  = (float*)(wsb + alloc((size_t)Nb * Hd * sizeof(float)));
    u16* XclsHi   = (u16*)(wsb + alloc((size_t)Nb * Hd * sizeof(u16)));
    u16* XclsLo   = (u16*)(wsb + alloc((size_t)Nb * Hd * sizeof(u16)));
    float* U      = (float*)(wsb + alloc((size_t)Nb * 2048 * sizeof(float)));
    u16* YHi      = (u16*)(wsb + alloc((size_t)Nb * 2048 * sizeof(u16)));
    u16* YLo      = (u16*)(wsb + alloc((size_t)Nb * 2048 * sizeof(u16)));
    u16* CcHi     = (u16*)(wsb + alloc((size_t)Nb * Hd * sizeof(u16)));
    u16* CcLo     = (u16*)(wsb + alloc((size_t)Nb * Hd * sizeof(u16)));
    float* Hb     = (float*)(wsb + alloc((size_t)Nb * Hd * sizeof(float)));
    u16* HbHi     = (u16*)(wsb + alloc((size_t)Nb * Hd * sizeof(u16)));
    u16* HbLo     = (u16*)(wsb + alloc((size_t)Nb * Hd * sizeof(u16)));
    u16* EHi      = (u16*)(wsb + alloc((size_t)Nb * 4096 * sizeof(u16)));
    u16* ELo      = (u16*)(wsb + alloc((size_t)Nb * 4096 * sizeof(u16)));
    float* Cp     = (float*)(wsb + alloc((size_t)4 * Nb * Hd * sizeof(float)));
    float* H2     = (float*)(wsb + alloc((size_t)Nb * Hd * sizeof(float)));

    hipMemsetAsync(zeros, 0, 2048 * sizeof(float), stream);

    // weight conversion (once per launch, deterministic)
    conv_w<<<dim3(32, 16),  256, 0, stream>>>(v1w, WvTHi,              WvTLo,              1024, 512);
    conv_w<<<dim3(32, 16),  256, 0, stream>>>(v2w, WvTHi + 512 * 1024, WvTLo + 512 * 1024, 1024, 512);
    conv_w<<<dim3(32, 32),  256, 0, stream>>>(pw,  WpTHi, WpTLo, 1024, 1024);
    conv_w<<<dim3(32, 128), 256, 0, stream>>>(w1w, W1THi, W1TLo, 1024, 4096);
    conv_w<<<dim3(128, 32), 256, 0, stream>>>(w2w, W2THi, W2TLo, 4096, 1024);
    conv_nat<<<256, 256, 0, stream>>>(k1w, WkNHi,              WkNLo);
    conv_nat<<<256, 256, 0, stream>>>(k2w, WkNHi + 1024 * 512, WkNLo + 1024 * 512);
    conv_nat<<<256, 256, 0, stream>>>(q1w, WqNHi,              WqNLo);
    conv_nat<<<256, 256, 0, stream>>>(q2w, WqNHi + 1024 * 512, WqNLo + 1024 * 512);

    // G_h = Wk_h @ Wq_h^T  (1024x1024, K=512) -> planes
    for (int h = 0; h < 2; ++h)
        gemm64<false, false, true, false><<<128, 256, 0, stream>>>(
            WkNHi + h * 1024 * 512, WkNLo + h * 1024 * 512, 512,
            WqNHi + h * 1024 * 512, WqNLo + h * 1024 * 512, 512,
            zeros, nullptr, 0, nullptr,
            GHi + (size_t)h * 1024 * 1024, GLo + (size_t)h * 1024 * 1024, 1024,
            1024, 512, nullptr, 0);

    cls_embed<<<Nb, 256, 0, stream>>>(toks, emb, pos, XclsF, XclsHi, XclsLo);

    // U = Xcls @ Gcat^T  (512 x 2048, K=1024)
    gemm64<false, false, false, false><<<128, 256, 0, stream>>>(
        XclsHi, XclsLo, 1024, GHi, GLo, 1024,
        zeros, nullptr, 0, U, nullptr, nullptr, 2048, 2048, 1024, nullptr, 0);

    attn_direct<<<Nb, 256, 0, stream>>>(toks, emb, pos, U, YHi, YLo);

    // attn_out_h = y_h @ Wv_h + bv_h -> Cc planes (col offset h*512)
    gemm64<false, false, true, false><<<32, 256, 0, stream>>>(
        YHi, YLo, 2048, WvTHi, WvTLo, 1024,
        v1b, nullptr, 0, nullptr, CcHi, CcLo, 1024, 512, 1024, nullptr, 0);
    gemm64<false, false, true, false><<<32, 256, 0, stream>>>(
        YHi + 1024, YLo + 1024, 2048, WvTHi + 512 * 1024, WvTLo + 512 * 1024, 1024,
        v2b, nullptr, 0, nullptr, CcHi + 512, CcLo + 512, 1024, 512, 1024, nullptr, 0);

    // Hb = Cc @ Wp + pb + Xcls
    gemm64<false, true, false, false><<<64, 256, 0, stream>>>(
        CcHi, CcLo, 1024, WpTHi, WpTLo, 1024,
        pb, XclsF, 1024, Hb, nullptr, nullptr, 1024, 1024, 1024, nullptr, 0);
    ln_kernel<<<Nb, 256, 0, stream>>>(Hb, lg, lb, HbHi, HbLo);

    // E = relu(Hb @ W1 + w1b) -> planes
    gemm64<true, false, true, false><<<256, 256, 0, stream>>>(
        HbHi, HbLo, 1024, W1THi, W1TLo, 1024,
        w1b, nullptr, 0, nullptr, EHi, ELo, 4096, 4096, 1024, nullptr, 0);

    // w2 split-K=4 partials
    gemm64<false, false, false, true><<<dim3(64, 1, 4), 256, 0, stream>>>(
        EHi, ELo, 4096, W2THi, W2TLo, 4096,
        nullptr, nullptr, 0, nullptr, nullptr, nullptr, 1024, 1024, 4096,
        Cp, (size_t)Nb * Hd);
    w2_reduce<<<512, 256, 0, stream>>>(Cp, w2b, Hb, H2);

    ln_final<<<Nb, 256, 0, stream>>>(H2, lg, lb, flw, flb, out);
}

// Round 5
// 254.156 us; speedup vs baseline: 33.9374x; 1.1061x over previous
//
#include <hip/hip_runtime.h>
#include <math.h>

typedef float  f32x4  __attribute__((ext_vector_type(4)));
typedef short  bf16x8 __attribute__((ext_vector_type(8)));
typedef unsigned short u16;
typedef unsigned int   u32;
typedef unsigned short u16x2 __attribute__((ext_vector_type(2)));
typedef unsigned short u16x4 __attribute__((ext_vector_type(4)));

constexpr int Tn = 43, Hd = 1024, Nb = 512;

__device__ __forceinline__ u16 f2bf(float f) {
    u32 u = __float_as_uint(f);
    u32 r = u + 0x7FFFu + ((u >> 16) & 1u);
    return (u16)(r >> 16);
}
__device__ __forceinline__ float bf2f(u16 h) {
    return __uint_as_float(((u32)h) << 16);
}

// ---------------------------------------------------------------------------
// segmented transposed weight conv: fp32 [K][N] -> bf16 hi/lo planes [N][K]
// ---------------------------------------------------------------------------
struct ConvT {
    const float* src[5];
    u16* dhi[5]; u16* dlo[5];
    int K[5], N[5], base[6];
};
__global__ __launch_bounds__(256)
void conv_T_all(ConvT a)
{
    __shared__ float tile[32][33];
    int id = blockIdx.x, seg = 0;
    while (seg < 4 && id >= a.base[seg + 1]) ++seg;
    const int local = id - a.base[seg];
    const int K = a.K[seg], N = a.N[seg];
    const int tn = N >> 5;
    const int k0 = (local / tn) << 5, n0 = (local % tn) << 5;
    const float* W = a.src[seg];
    const int t = threadIdx.x;
    {
        int kk = t >> 3, nn = (t & 7) * 4;
        float4 v = *(const float4*)(W + (size_t)(k0 + kk) * N + n0 + nn);
        tile[kk][nn] = v.x; tile[kk][nn + 1] = v.y;
        tile[kk][nn + 2] = v.z; tile[kk][nn + 3] = v.w;
    }
    __syncthreads();
    {
        int nn = t >> 3, kk = (t & 7) * 4;
        u16x4 h, l;
        #pragma unroll
        for (int j = 0; j < 4; ++j) {
            float f = tile[kk + j][nn];
            u16 hh = f2bf(f);
            h[j] = hh;
            l[j] = f2bf(f - bf2f(hh));
        }
        size_t o = (size_t)(n0 + nn) * K + k0 + kk;
        *(u16x4*)(a.dhi[seg] + o) = h;
        *(u16x4*)(a.dlo[seg] + o) = l;
    }
}

// ---------------------------------------------------------------------------
// segmented natural conv: fp32 flat 1024x512 -> hi/lo planes (4 segments)
// ---------------------------------------------------------------------------
struct ConvN { const float* src[4]; u16* dhi[4]; u16* dlo[4]; };
__global__ __launch_bounds__(256)
void conv_nat_all(ConvN a)
{
    const int seg = blockIdx.x >> 8, local = blockIdx.x & 255;
    const size_t e = ((size_t)local * 256 + threadIdx.x) * 8;
    const float4* p = (const float4*)(a.src[seg] + e);
    float4 v0 = p[0], v1 = p[1];
    float f[8] = {v0.x, v0.y, v0.z, v0.w, v1.x, v1.y, v1.z, v1.w};
    u16 hv[8], lv[8];
    #pragma unroll
    for (int j = 0; j < 8; ++j) {
        u16 h = f2bf(f[j]);
        hv[j] = h;
        lv[j] = f2bf(f[j] - bf2f(h));
    }
    *(u16x4*)(a.dhi[seg] + e)     = *(u16x4*)&hv[0];
    *(u16x4*)(a.dhi[seg] + e + 4) = *(u16x4*)&hv[4];
    *(u16x4*)(a.dlo[seg] + e)     = *(u16x4*)&lv[0];
    *(u16x4*)(a.dlo[seg] + e + 4) = *(u16x4*)&lv[4];
}

// ---------------------------------------------------------------------------
// misc: A64 planes (row0 = [v1b|v2b], rows 1..63 zero) + bq = [q1b|q2b]
// grid 64 blocks; block r handles row r.
// ---------------------------------------------------------------------------
__global__ __launch_bounds__(256)
void misc_kernel(const float* __restrict__ v1b, const float* __restrict__ v2b,
                 const float* __restrict__ q1b, const float* __restrict__ q2b,
                 u16* __restrict__ AHi, u16* __restrict__ ALo,
                 float* __restrict__ bq)
{
    const int r = blockIdx.x, t = threadIdx.x;
    u16x4 hv = {0, 0, 0, 0}, lv = {0, 0, 0, 0};
    if (r == 0) {
        #pragma unroll
        for (int j = 0; j < 4; ++j) {
            int c = t * 4 + j;
            float f = (c < 512) ? v1b[c] : v2b[c - 512];
            u16 h = f2bf(f);
            hv[j] = h;
            lv[j] = f2bf(f - bf2f(h));
        }
    }
    *(u16x4*)(AHi + (size_t)r * 1024 + t * 4) = hv;
    *(u16x4*)(ALo + (size_t)r * 1024 + t * 4) = lv;
    if (r == 1) {
        for (int i = t; i < 512; i += 256) {
            bq[i] = q1b[i];
            bq[512 + i] = q2b[i];
        }
    }
}

// ---------------------------------------------------------------------------
// CLS embed: x = emb[tok[n,0]] + pos[0] -> fp32 + bf16 hi/lo planes
// ---------------------------------------------------------------------------
__global__ __launch_bounds__(256)
void cls_embed(const int* __restrict__ toks, const float* __restrict__ emb,
               const float* __restrict__ pos, float* __restrict__ Xf,
               u16* __restrict__ XHi, u16* __restrict__ XLo)
{
    const int n = blockIdx.x, i = threadIdx.x;
    const int tok = toks[n * Tn];
    float4 e = ((const float4*)(emb + (size_t)tok * Hd))[i];
    float4 p = ((const float4*)pos)[i];
    float f[4] = {e.x + p.x, e.y + p.y, e.z + p.z, e.w + p.w};
    ((float4*)(Xf + (size_t)n * Hd))[i] = make_float4(f[0], f[1], f[2], f[3]);
    u16x4 hv, lv;
    #pragma unroll
    for (int j = 0; j < 4; ++j) {
        u16 h = f2bf(f[j]);
        hv[j] = h;
        lv[j] = f2bf(f[j] - bf2f(h));
    }
    *(u16x4*)(XHi + (size_t)n * Hd + i * 4) = hv;
    *(u16x4*)(XLo + (size_t)n * Hd + i * 4) = lv;
}

// ---------------------------------------------------------------------------
// MFMA GEMM, 3-term split, 64x128 tile, BK=32, 4 waves.
// Fragment-major LDS with kk-XOR bank swizzle (conflict-free b128 R+W).
// z-batching: pointer offsets az/bz/cz per blockIdx.z (heads), or SPLIT-K.
// ---------------------------------------------------------------------------
template<bool RELU, bool HASRES, bool PLANES, bool SPLIT>
__global__ __launch_bounds__(256, 2)
void gemm64(const u16* __restrict__ Ahi, const u16* __restrict__ Alo, int lda,
            size_t az,
            const u16* __restrict__ Bhi, const u16* __restrict__ Blo, int ldb,
            size_t bz,
            const float* __restrict__ bias, const float* __restrict__ res,
            int ldres, float* __restrict__ C, u16* __restrict__ CHi,
            u16* __restrict__ CLo, int ldc, size_t cz, int N, int K,
            float* __restrict__ Cp, size_t pstride)
{
    __shared__ uint4 lds4[1536];          // 24 KB: Ahi 4K | Alo 4K | Bhi 8K | Blo 8K
    char* lds = (char*)lds4;
    const int tid = threadIdx.x;

    const int nbx = gridDim.x;
    const int q8 = nbx >> 3;
    const int sw = (blockIdx.x & 7) * q8 + (blockIdx.x >> 3);
    const int ncol = N >> 7;
    const int bm = (sw / ncol) << 6, bn = (sw % ncol) << 7;

    int kc = K, kb = 0;
    if (SPLIT) {
        kc = K / gridDim.z; kb = blockIdx.z * kc;
    } else {
        Ahi += blockIdx.z * az; Alo += blockIdx.z * az;
        Bhi += blockIdx.z * bz; Blo += blockIdx.z * bz;
    }

    const int ra = tid >> 2, ga = tid & 3;
    const int rb = tid >> 1, gb = (tid & 1) << 1;
    const u16* pAh = Ahi + (size_t)(bm + ra) * lda + kb + ga * 8;
    const u16* pAl = Alo + (size_t)(bm + ra) * lda + kb + ga * 8;
    const u16* pBh = Bhi + (size_t)(bn + rb) * ldb + kb + gb * 8;
    const u16* pBl = Blo + (size_t)(bn + rb) * ldb + kb + gb * 8;

    // bank-conflict-free chunk addresses: row slot XOR'd with 2*kk
    const int wA  = ((ra >> 4) << 10) | (ga << 8) | ((((ra & 15) ^ (ga << 1)) & 15) << 4);
    const int wB0 = ((rb >> 4) << 10) | (gb << 8) | ((((rb & 15) ^ (gb << 1)) & 15) << 4);
    const int wB1 = ((rb >> 4) << 10) | ((gb + 1) << 8) | ((((rb & 15) ^ ((gb + 1) << 1)) & 15) << 4);

    const int wv = tid >> 6, lane = tid & 63;
    const int wr = wv >> 1, wc = wv & 1;
    const int l15 = lane & 15, l4 = lane >> 4;
    const int rsw = (l15 ^ (l4 << 1)) << 4;

    int fA[2], fB[4];
    #pragma unroll
    for (int m = 0; m < 2; ++m)
        fA[m] = (((wr << 1) + m) << 10) | (l4 << 8) | rsw;
    #pragma unroll
    for (int n = 0; n < 4; ++n)
        fB[n] = (((wc << 2) + n) << 10) | (l4 << 8) | rsw;

    f32x4 acc[2][4] = {};

    uint4 sAh = *(const uint4*)pAh;
    uint4 sAl = *(const uint4*)pAl;
    uint4 sBh0 = *(const uint4*)pBh, sBh1 = *(const uint4*)(pBh + 8);
    uint4 sBl0 = *(const uint4*)pBl, sBl1 = *(const uint4*)(pBl + 8);

    for (int k0 = 0; k0 < kc; k0 += 32) {
        __syncthreads();
        *(uint4*)(lds + wA)          = sAh;
        *(uint4*)(lds + 4096 + wA)   = sAl;
        *(uint4*)(lds + 8192 + wB0)  = sBh0;
        *(uint4*)(lds + 8192 + wB1)  = sBh1;
        *(uint4*)(lds + 16384 + wB0) = sBl0;
        *(uint4*)(lds + 16384 + wB1) = sBl1;
        __syncthreads();
        if (k0 + 32 < kc) {
            pAh += 32; pAl += 32; pBh += 32; pBl += 32;
            sAh = *(const uint4*)pAh;
            sAl = *(const uint4*)pAl;
            sBh0 = *(const uint4*)pBh; sBh1 = *(const uint4*)(pBh + 8);
            sBl0 = *(const uint4*)pBl; sBl1 = *(const uint4*)(pBl + 8);
        }
        bf16x8 ah[2], al[2], bh[4], bl[4];
        #pragma unroll
        for (int m = 0; m < 2; ++m) {
            ah[m] = *(const bf16x8*)(lds + fA[m]);
            al[m] = *(const bf16x8*)(lds + 4096 + fA[m]);
        }
        #pragma unroll
        for (int n = 0; n < 4; ++n) {
            bh[n] = *(const bf16x8*)(lds + 8192 + fB[n]);
            bl[n] = *(const bf16x8*)(lds + 16384 + fB[n]);
        }
        #pragma unroll
        for (int m = 0; m < 2; ++m)
            #pragma unroll
            for (int n = 0; n < 4; ++n) {
                acc[m][n] = __builtin_amdgcn_mfma_f32_16x16x32_bf16(ah[m], bh[n], acc[m][n], 0, 0, 0);
                acc[m][n] = __builtin_amdgcn_mfma_f32_16x16x32_bf16(al[m], bh[n], acc[m][n], 0, 0, 0);
                acc[m][n] = __builtin_amdgcn_mfma_f32_16x16x32_bf16(ah[m], bl[n], acc[m][n], 0, 0, 0);
            }
    }

    #pragma unroll
    for (int n = 0; n < 4; ++n) {
        const int col = bn + (wc << 6) + n * 16 + l15;
        const float bv = SPLIT ? 0.f : bias[col];
        const int colz = SPLIT ? col : col + (int)(blockIdx.z * cz);
        #pragma unroll
        for (int m = 0; m < 2; ++m) {
            const int row0 = bm + (wr << 5) + m * 16 + l4 * 4;
            #pragma unroll
            for (int rg = 0; rg < 4; ++rg) {
                const int row = row0 + rg;
                float v = acc[m][n][rg];
                if (SPLIT) {
                    Cp[blockIdx.z * pstride + (size_t)row * N + col] = v;
                } else {
                    v += bv;
                    if (HASRES) v += res[(size_t)row * ldres + col];
                    if (RELU)   v = fmaxf(v, 0.f);
                    if (PLANES) {
                        u16 hh = f2bf(v);
                        CHi[(size_t)row * ldc + colz] = hh;
                        CLo[(size_t)row * ldc + colz] = f2bf(v - bf2f(hh));
                    } else {
                        C[(size_t)row * ldc + colz] = v;
                    }
                }
            }
        }
    }
}

// ---------------------------------------------------------------------------
// fused CLS attention from the embedding gather.
// scores_sh = x_s . u_h / sqrt(512)   (K-bias shift cancels in softmax)
// y_h = sum_s p_sh x_s  -> bf16 planes Y[n][2048] = [y1|y2]
// one block (512 threads) per sequence.
// ---------------------------------------------------------------------------
__global__ __launch_bounds__(512)
void attn_direct(const int* __restrict__ toks, const float* __restrict__ emb,
                 const float* __restrict__ pos, const float* __restrict__ U,
                 u16* __restrict__ YHi, u16* __restrict__ YLo)
{
    const int n = blockIdx.x, tid = threadIdx.x;
    __shared__ float us[2048];
    __shared__ float ps[2][48];
    ((float4*)us)[tid] = ((const float4*)(U + (size_t)n * 2048))[tid];
    __syncthreads();

    const int wave = tid >> 6, lane = tid & 63;
    const int* tk = toks + n * Tn;

    for (int s = wave; s < Tn; s += 8) {
        const int tok = tk[s];
        const float4* er = (const float4*)(emb + (size_t)tok * Hd);
        const float4* pr = (const float4*)(pos + (size_t)s * Hd);
        float d1 = 0.f, d2 = 0.f;
        #pragma unroll
        for (int i = 0; i < 4; ++i) {
            const int c = i * 64 + lane;
            float4 e = er[c], p = pr[c];
            float x0 = e.x + p.x, x1 = e.y + p.y, x2 = e.z + p.z, x3 = e.w + p.w;
            const float* u1 = us + c * 4;
            const float* u2 = us + 1024 + c * 4;
            d1 += x0 * u1[0] + x1 * u1[1] + x2 * u1[2] + x3 * u1[3];
            d2 += x0 * u2[0] + x1 * u2[1] + x2 * u2[2] + x3 * u2[3];
        }
        #pragma unroll
        for (int off = 32; off; off >>= 1) {
            d1 += __shfl_xor(d1, off);
            d2 += __shfl_xor(d2, off);
        }
        if (lane == 0) {
            ps[0][s] = d1 * 0.044194173824159216f;
            ps[1][s] = d2 * 0.044194173824159216f;
        }
    }
    __syncthreads();
    if (wave < 2) {
        float v = (lane < Tn) ? ps[wave][lane] : -INFINITY;
        float mx = v;
        #pragma unroll
        for (int off = 32; off; off >>= 1) mx = fmaxf(mx, __shfl_xor(mx, off));
        float e = (lane < Tn) ? __expf(v - mx) : 0.f;
        float sum = e;
        #pragma unroll
        for (int off = 32; off; off >>= 1) sum += __shfl_xor(sum, off);
        if (lane < Tn) ps[wave][lane] = e / sum;
    }
    __syncthreads();

    // weighted sum with 2-deep prefetch; thread owns 2 columns
    const int c2 = tid * 2;
    float2 a1 = make_float2(0.f, 0.f), a2 = make_float2(0.f, 0.f);
    float2 e = *(const float2*)(emb + (size_t)tk[0] * Hd + c2);
    float2 p = *(const float2*)(pos + c2);
    for (int s = 0; s < Tn; ++s) {
        float2 en = make_float2(0.f, 0.f), pn = en;
        if (s + 1 < Tn) {
            en = *(const float2*)(emb + (size_t)tk[s + 1] * Hd + c2);
            pn = *(const float2*)(pos + (size_t)(s + 1) * Hd + c2);
        }
        const float p1 = ps[0][s], p2 = ps[1][s];
        const float x0 = e.x + p.x, x1 = e.y + p.y;
        a1.x = fmaf(p1, x0, a1.x); a1.y = fmaf(p1, x1, a1.y);
        a2.x = fmaf(p2, x0, a2.x); a2.y = fmaf(p2, x1, a2.y);
        e = en; p = pn;
    }
    u16x2 h1, l1, h2, l2;
    u16 h;
    h = f2bf(a1.x); h1[0] = h; l1[0] = f2bf(a1.x - bf2f(h));
    h = f2bf(a1.y); h1[1] = h; l1[1] = f2bf(a1.y - bf2f(h));
    h = f2bf(a2.x); h2[0] = h; l2[0] = f2bf(a2.x - bf2f(h));
    h = f2bf(a2.y); h2[1] = h; l2[1] = f2bf(a2.y - bf2f(h));
    const size_t o = (size_t)n * 2048 + c2;
    *(u16x2*)(YHi + o) = h1;          *(u16x2*)(YLo + o) = l1;
    *(u16x2*)(YHi + o + 1024) = h2;   *(u16x2*)(YLo + o + 1024) = l2;
}

// ---------------------------------------------------------------------------
// LayerNorm: in-place fp32 + bf16 hi/lo planes out. one block per row.
// ---------------------------------------------------------------------------
__global__ __launch_bounds__(256)
void ln_kernel(float* __restrict__ X, const float* __restrict__ g,
               const float* __restrict__ b, u16* __restrict__ PHi,
               u16* __restrict__ PLo)
{
    const int tid = threadIdx.x;
    float4* row = (float4*)(X + (size_t)blockIdx.x * Hd);
    float4 v = row[tid];
    float s = v.x + v.y + v.z + v.w;
    float q = v.x*v.x + v.y*v.y + v.z*v.z + v.w*v.w;
    #pragma unroll
    for (int off = 32; off; off >>= 1) {
        s += __shfl_xor(s, off);
        q += __shfl_xor(q, off);
    }
    __shared__ float ss[4], sq[4];
    const int lane = tid & 63, w = tid >> 6;
    if (lane == 0) { ss[w] = s; sq[w] = q; }
    __syncthreads();
    s = ss[0] + ss[1] + ss[2] + ss[3];
    q = sq[0] + sq[1] + sq[2] + sq[3];
    const float mean = s * (1.f / Hd);
    const float var = q * (1.f / Hd) - mean * mean;
    const float rstd = rsqrtf(var + 1e-5f);
    float4 gv = ((const float4*)g)[tid];
    float4 bv = ((const float4*)b)[tid];
    float f[4];
    f[0] = (v.x - mean) * rstd * gv.x + bv.x;
    f[1] = (v.y - mean) * rstd * gv.y + bv.y;
    f[2] = (v.z - mean) * rstd * gv.z + bv.z;
    f[3] = (v.w - mean) * rstd * gv.w + bv.w;
    row[tid] = make_float4(f[0], f[1], f[2], f[3]);
    u16x4 hv, lv;
    #pragma unroll
    for (int j = 0; j < 4; ++j) {
        u16 hh = f2bf(f[j]);
        hv[j] = hh;
        lv[j] = f2bf(f[j] - bf2f(hh));
    }
    *(u16x4*)(PHi + (size_t)blockIdx.x * Hd + tid * 4) = hv;
    *(u16x4*)(PLo + (size_t)blockIdx.x * Hd + tid * 4) = lv;
}

// ---------------------------------------------------------------------------
// fused: H2 = sum_z Cp[z] + w2b + Hb ; LN ; dot(fl_w) ; sigmoid -> out[n]
// one block per sequence.
// ---------------------------------------------------------------------------
__global__ __launch_bounds__(256)
void w2ln_final(const float* __restrict__ Cp, const float* __restrict__ w2b,
                const float* __restrict__ Hb, const float* __restrict__ g,
                const float* __restrict__ b, const float* __restrict__ fw,
                const float* __restrict__ fb, float* __restrict__ out)
{
    const int tid = threadIdx.x;
    const size_t base = (size_t)blockIdx.x * Hd;
    const size_t P = (size_t)Nb * Hd;
    float4 v0 = ((const float4*)(Cp + base))[tid];
    float4 v1 = ((const float4*)(Cp + P + base))[tid];
    float4 v2 = ((const float4*)(Cp + 2 * P + base))[tid];
    float4 v3 = ((const float4*)(Cp + 3 * P + base))[tid];
    float4 bb = ((const float4*)w2b)[tid];
    float4 hh = ((const float4*)(Hb + base))[tid];
    float4 v;
    v.x = v0.x + v1.x + v2.x + v3.x + bb.x + hh.x;
    v.y = v0.y + v1.y + v2.y + v3.y + bb.y + hh.y;
    v.z = v0.z + v1.z + v2.z + v3.z + bb.z + hh.z;
    v.w = v0.w + v1.w + v2.w + v3.w + bb.w + hh.w;

    float s = v.x + v.y + v.z + v.w;
    float q = v.x*v.x + v.y*v.y + v.z*v.z + v.w*v.w;
    #pragma unroll
    for (int off = 32; off; off >>= 1) {
        s += __shfl_xor(s, off);
        q += __shfl_xor(q, off);
    }
    __shared__ float ss[4], sq[4], sd[4];
    const int lane = tid & 63, w = tid >> 6;
    if (lane == 0) { ss[w] = s; sq[w] = q; }
    __syncthreads();
    s = ss[0] + ss[1] + ss[2] + ss[3];
    q = sq[0] + sq[1] + sq[2] + sq[3];
    const float mean = s * (1.f / Hd);
    const float var = q * (1.f / Hd) - mean * mean;
    const float rstd = rsqrtf(var + 1e-5f);
    float4 gv = ((const float4*)g)[tid];
    float4 bv = ((const float4*)b)[tid];
    float4 wv = ((const float4*)fw)[tid];
    float d = ((v.x - mean) * rstd * gv.x + bv.x) * wv.x
            + ((v.y - mean) * rstd * gv.y + bv.y) * wv.y
            + ((v.z - mean) * rstd * gv.z + bv.z) * wv.z
            + ((v.w - mean) * rstd * gv.w + bv.w) * wv.w;
    #pragma unroll
    for (int off = 32; off; off >>= 1) d += __shfl_xor(d, off);
    if (lane == 0) sd[w] = d;
    __syncthreads();
    if (tid == 0) {
        float z = sd[0] + sd[1] + sd[2] + sd[3] + fb[0];
        out[blockIdx.x] = 1.f / (1.f + expf(-z));
    }
}

// ---------------------------------------------------------------------------
// host
// ---------------------------------------------------------------------------
extern "C" void kernel_launch(void* const* d_in, const int* in_sizes, int n_in,
                              void* d_out, int out_size, void* d_ws, size_t ws_size,
                              hipStream_t stream)
{
    const int*   toks = (const int*)d_in[0];
    const float* emb  = (const float*)d_in[1];
    const float* pos  = (const float*)d_in[2];
    const float* q1w = (const float*)d_in[3];  const float* q1b = (const float*)d_in[4];
    const float* k1w = (const float*)d_in[5];
    const float* v1w = (const float*)d_in[7];  const float* v1b = (const float*)d_in[8];
    const float* q2w = (const float*)d_in[9];  const float* q2b = (const float*)d_in[10];
    const float* k2w = (const float*)d_in[11];
    const float* v2w = (const float*)d_in[13]; const float* v2b = (const float*)d_in[14];
    const float* pw  = (const float*)d_in[15]; const float* pb  = (const float*)d_in[16];
    const float* lg  = (const float*)d_in[17]; const float* lb  = (const float*)d_in[18];
    const float* w1w = (const float*)d_in[19]; const float* w1b = (const float*)d_in[20];
    const float* w2w = (const float*)d_in[21]; const float* w2b = (const float*)d_in[22];
    const float* flw = (const float*)d_in[23]; const float* flb = (const float*)d_in[24];
    float* out = (float*)d_out;
    char* wsb  = (char*)d_ws;

    size_t off = 0;
    auto alloc = [&](size_t bytes) { size_t o = off; off = (off + bytes + 255) & ~(size_t)255; return o; };

    // weight planes
    u16* WqTHi = (u16*)(wsb + alloc(1024 * 1024 * sizeof(u16)));   // [1024 q-dims][1024]
    u16* WqTLo = (u16*)(wsb + alloc(1024 * 1024 * sizeof(u16)));
    u16* WpTHi = (u16*)(wsb + alloc(1024 * 1024 * sizeof(u16)));
    u16* WpTLo = (u16*)(wsb + alloc(1024 * 1024 * sizeof(u16)));
    u16* W1THi = (u16*)(wsb + alloc(4096 * 1024 * sizeof(u16)));
    u16* W1TLo = (u16*)(wsb + alloc(4096 * 1024 * sizeof(u16)));
    u16* W2THi = (u16*)(wsb + alloc(1024 * 4096 * sizeof(u16)));
    u16* W2TLo = (u16*)(wsb + alloc(1024 * 4096 * sizeof(u16)));
    u16* WkNHi = (u16*)(wsb + alloc(2 * 1024 * 512 * sizeof(u16)));
    u16* WkNLo = (u16*)(wsb + alloc(2 * 1024 * 512 * sizeof(u16)));
    u16* WvNHi = (u16*)(wsb + alloc(2 * 1024 * 512 * sizeof(u16)));
    u16* WvNLo = (u16*)(wsb + alloc(2 * 1024 * 512 * sizeof(u16)));
    u16* WvpHi = (u16*)(wsb + alloc(1024 * 2048 * sizeof(u16)));   // [1024 j][2048 c]
    u16* WvpLo = (u16*)(wsb + alloc(1024 * 2048 * sizeof(u16)));
    u16* A64Hi = (u16*)(wsb + alloc(64 * 1024 * sizeof(u16)));
    u16* A64Lo = (u16*)(wsb + alloc(64 * 1024 * sizeof(u16)));
    float* Bvp64 = (float*)(wsb + alloc(64 * 1024 * sizeof(float)));
    float* bq    = (float*)(wsb + alloc(1024 * sizeof(float)));
    float* zeros = (float*)(wsb + alloc(2048 * sizeof(float)));

    // activations (M = 512)
    float* XclsF = (float*)(wsb + alloc((size_t)Nb * Hd * sizeof(float)));
    u16* XclsHi  = (u16*)(wsb + alloc((size_t)Nb * Hd * sizeof(u16)));
    u16* XclsLo  = (u16*)(wsb + alloc((size_t)Nb * Hd * sizeof(u16)));
    u16* QplHi   = (u16*)(wsb + alloc((size_t)Nb * Hd * sizeof(u16)));
    u16* QplLo   = (u16*)(wsb + alloc((size_t)Nb * Hd * sizeof(u16)));
    float* U     = (float*)(wsb + alloc((size_t)Nb * 2048 * sizeof(float)));
    u16* YHi     = (u16*)(wsb + alloc((size_t)Nb * 2048 * sizeof(u16)));
    u16* YLo     = (u16*)(wsb + alloc((size_t)Nb * 2048 * sizeof(u16)));
    float* Hb    = (float*)(wsb + alloc((size_t)Nb * Hd * sizeof(float)));
    u16* HbHi    = (u16*)(wsb + alloc((size_t)Nb * Hd * sizeof(u16)));
    u16* HbLo    = (u16*)(wsb + alloc((size_t)Nb * Hd * sizeof(u16)));
    u16* EHi     = (u16*)(wsb + alloc((size_t)Nb * 4096 * sizeof(u16)));
    u16* ELo     = (u16*)(wsb + alloc((size_t)Nb * 4096 * sizeof(u16)));
    float* Cp    = (float*)(wsb + alloc((size_t)4 * Nb * Hd * sizeof(float)));

    hipMemsetAsync(zeros, 0, 2048 * sizeof(float), stream);

    // ---- weight conversion (2 dispatches) ----
    ConvT ct;
    ct.src[0] = q1w; ct.dhi[0] = WqTHi;              ct.dlo[0] = WqTLo;              ct.K[0] = 1024; ct.N[0] = 512;
    ct.src[1] = q2w; ct.dhi[1] = WqTHi + 512 * 1024; ct.dlo[1] = WqTLo + 512 * 1024; ct.K[1] = 1024; ct.N[1] = 512;
    ct.src[2] = pw;  ct.dhi[2] = WpTHi;              ct.dlo[2] = WpTLo;              ct.K[2] = 1024; ct.N[2] = 1024;
    ct.src[3] = w1w; ct.dhi[3] = W1THi;              ct.dlo[3] = W1TLo;              ct.K[3] = 1024; ct.N[3] = 4096;
    ct.src[4] = w2w; ct.dhi[4] = W2THi;              ct.dlo[4] = W2TLo;              ct.K[4] = 4096; ct.N[4] = 1024;
    ct.base[0] = 0;
    for (int i = 0; i < 5; ++i)
        ct.base[i + 1] = ct.base[i] + (ct.K[i] / 32) * (ct.N[i] / 32);
    conv_T_all<<<ct.base[5], 256, 0, stream>>>(ct);

    ConvN cn;
    cn.src[0] = k1w; cn.dhi[0] = WkNHi;              cn.dlo[0] = WkNLo;
    cn.src[1] = k2w; cn.dhi[1] = WkNHi + 1024 * 512; cn.dlo[1] = WkNLo + 1024 * 512;
    cn.src[2] = v1w; cn.dhi[2] = WvNHi;              cn.dlo[2] = WvNLo;
    cn.src[3] = v2w; cn.dhi[3] = WvNHi + 1024 * 512; cn.dlo[3] = WvNLo + 1024 * 512;
    conv_nat_all<<<1024, 256, 0, stream>>>(cn);

    misc_kernel<<<64, 256, 0, stream>>>(v1b, v2b, q1b, q2b, A64Hi, A64Lo, bq);

    // bvp row: Bvp64[0][:] = [v1b|v2b] @ Wp + pb   (M=64, N=1024, K=1024)
    gemm64<false, false, false, false><<<8, 256, 0, stream>>>(
        A64Hi, A64Lo, 1024, 0, WpTHi, WpTLo, 1024, 0,
        pb, nullptr, 0, Bvp64, nullptr, nullptr, 1024, 0, 1024, 1024, nullptr, 0);

    // WvpT[j][h*1024+r] = (Wv_h @ Wp_half)[r][j]   (z=2 heads, M=1024,N=1024,K=512)
    gemm64<false, false, true, false><<<dim3(128, 1, 2), 256, 0, stream>>>(
        WpTHi, WpTLo, 1024, 512, WvNHi, WvNLo, 512, (size_t)1024 * 512,
        zeros, nullptr, 0, nullptr, WvpHi, WvpLo, 2048, 1024, 1024, 512, nullptr, 0);

    cls_embed<<<Nb, 256, 0, stream>>>(toks, emb, pos, XclsF, XclsHi, XclsLo);

    // Q = Xcls @ Wq + bq  (M=512, N=1024, K=1024) -> planes
    gemm64<false, false, true, false><<<64, 256, 0, stream>>>(
        XclsHi, XclsLo, 1024, 0, WqTHi, WqTLo, 1024, 0,
        bq, nullptr, 0, nullptr, QplHi, QplLo, 1024, 0, 1024, 1024, nullptr, 0);

    // U_h = Q_h @ Wk_h^T  (z=2, M=512, N=1024, K=512) -> fp32 [512][2048]
    gemm64<false, false, false, false><<<dim3(64, 1, 2), 256, 0, stream>>>(
        QplHi, QplLo, 1024, 512, WkNHi, WkNLo, 512, (size_t)1024 * 512,
        zeros, nullptr, 0, U, nullptr, nullptr, 2048, 1024, 1024, 512, nullptr, 0);

    attn_direct<<<Nb, 512, 0, stream>>>(toks, emb, pos, U, YHi, YLo);

    // Hb = Y @ WvpT^T + bvp + Xcls  (M=512, N=1024, K=2048)
    gemm64<false, true, false, false><<<64, 256, 0, stream>>>(
        YHi, YLo, 2048, 0, WvpHi, WvpLo, 2048, 0,
        Bvp64, XclsF, 1024, Hb, nullptr, nullptr, 1024, 0, 1024, 2048, nullptr, 0);

    ln_kernel<<<Nb, 256, 0, stream>>>(Hb, lg, lb, HbHi, HbLo);

    // E = relu(Hb @ W1 + w1b) -> planes  (M=512, N=4096, K=1024)
    gemm64<true, false, true, false><<<256, 256, 0, stream>>>(
        HbHi, HbLo, 1024, 0, W1THi, W1TLo, 1024, 0,
        w1b, nullptr, 0, nullptr, EHi, ELo, 4096, 0, 4096, 1024, nullptr, 0);

    // w2 split-K=4 partials  (M=512, N=1024, K=4096)
    gemm64<false, false, false, true><<<dim3(64, 1, 4), 256, 0, stream>>>(
        EHi, ELo, 4096, 0, W2THi, W2TLo, 4096, 0,
        nullptr, nullptr, 0, nullptr, nullptr, nullptr, 1024, 0, 1024, 4096,
        Cp, (size_t)Nb * Hd);

    w2ln_final<<<Nb, 256, 0, stream>>>(Cp, w2b, Hb, lg, lb, flw, flb, out);
}